// Round 1
// 609.603 us; speedup vs baseline: 1.1636x; 1.1636x over previous
//
#include <hip/hip_runtime.h>
#include <cstdint>
#include <cstddef>

#define NN 100000
#define NE 1600000
#define NBB 391   // dst buckets of 256 nodes: ceil(100000/256)

typedef short short8 __attribute__((ext_vector_type(8)));
typedef float floatx4 __attribute__((ext_vector_type(4)));
typedef unsigned short u16;

// ---------------- graph preprocessing (bucketed, atomic-light) ----------------
// Round-5 lesson: 25-bucket k_bfill = 4% occupancy (25 blocks) -> 189 us.
// Bucket at 256-node granularity (391 blocks), ranks via LDS atomics.

static __global__ void k_zero(int* __restrict__ gh) {
    int i = threadIdx.x;
    if (i < NBB + 1) gh[i] = 0;
}

// histogram of dst>>8 ; 1024 thr x 4 edges/block -> 391 global atomics/block
static __global__ __launch_bounds__(1024) void k_bhist(const int* __restrict__ dst,
                                                       int* __restrict__ gh) {
    __shared__ int h[NBB + 1];
    int t = threadIdx.x;
    for (int i = t; i < NBB; i += 1024) h[i] = 0;
    __syncthreads();
    int e0 = blockIdx.x * 4096;
#pragma unroll
    for (int j = 0; j < 4; j++) {
        int e = e0 + j * 1024 + t;
        if (e < NE) atomicAdd(&h[dst[e] >> 8], 1);
    }
    __syncthreads();
    for (int i = t; i < NBB; i += 1024)
        if (h[i]) atomicAdd(&gh[i], h[i]);
}

// parallel single-block scan over NBB=391 bucket counts (was serial 1-thread loop)
static __global__ void k_bscan(const int* __restrict__ gh, int* __restrict__ gbase,
                               int* __restrict__ gcur) {
    __shared__ int sd[512];
    int t = threadIdx.x;
    int v = (t < NBB) ? gh[t] : 0;
    sd[t] = v;
    __syncthreads();
    for (int off = 1; off < 512; off <<= 1) {
        int x = (t >= off) ? sd[t - off] : 0;
        __syncthreads();
        sd[t] += x;
        __syncthreads();
    }
    int excl = (t > 0) ? sd[t - 1] : 0;
    if (t < NBB) {
        gbase[t] = excl;
        gcur[t] = excl;
    }
    if (t == NBB) gbase[NBB] = excl;  // == NE
}

// scatter edges into bucket-ordered staging (int2 = src,dst)
static __global__ __launch_bounds__(1024) void k_bscatter(const int* __restrict__ src,
                                                          const int* __restrict__ dst,
                                                          int* __restrict__ gcur,
                                                          int2* __restrict__ staging) {
    __shared__ int h[NBB + 1];
    __shared__ int base[NBB + 1];
    int t = threadIdx.x;
    for (int i = t; i < NBB; i += 1024) h[i] = 0;
    __syncthreads();
    int e0 = blockIdx.x * 4096;
    int b[4], l[4], sv[4], dv[4];
#pragma unroll
    for (int j = 0; j < 4; j++) {
        int e = e0 + j * 1024 + t;
        b[j] = -1;
        if (e < NE) {
            sv[j] = src[e];
            dv[j] = dst[e];
            b[j] = dv[j] >> 8;
            l[j] = atomicAdd(&h[b[j]], 1);
        }
    }
    __syncthreads();
    for (int i = t; i < NBB; i += 1024)
        if (h[i]) base[i] = atomicAdd(&gcur[i], h[i]);
    __syncthreads();
#pragma unroll
    for (int j = 0; j < 4; j++)
        if (b[j] >= 0) staging[base[b[j]] + l[j]] = make_int2(sv[j], dv[j]);
}

// per-bucket degree count via LDS -> deg/dinv written coalesced, no global atomics
static __global__ __launch_bounds__(1024) void k_blocal(const int2* __restrict__ staging,
                                                        const int* __restrict__ gbase,
                                                        int* __restrict__ deg,
                                                        float* __restrict__ dinv) {
    __shared__ int cnt[256];
    int b = blockIdx.x;
    int t = threadIdx.x;
    if (t < 256) cnt[t] = 0;
    __syncthreads();
    int end = gbase[b + 1];
    for (int i = gbase[b] + t; i < end; i += 1024)
        atomicAdd(&cnt[staging[i].y & 255], 1);
    __syncthreads();
    if (t < 256) {
        int node = (b << 8) + t;
        if (node < NN) {
            int d = cnt[t] + 1;  // +1 self loop
            deg[node] = d;
            dinv[node] = rsqrtf((float)d);
        }
    }
}

// exclusive scan of (deg[i]-1) -> row_ptr, chunk=1024/block
static __global__ void k_scan1(const int* __restrict__ deg, int* __restrict__ row_ptr,
                               int* __restrict__ bsums) {
    __shared__ int sd[256];
    int t = threadIdx.x;
    int base = blockIdx.x * 1024;
    int v[4];
    int s = 0;
#pragma unroll
    for (int j = 0; j < 4; j++) {
        int i = base + t * 4 + j;
        int c = (i < NN) ? (deg[i] - 1) : 0;
        v[j] = s;
        s += c;
    }
    sd[t] = s;
    __syncthreads();
    for (int off = 1; off < 256; off <<= 1) {
        int x = (t >= off) ? sd[t - off] : 0;
        __syncthreads();
        sd[t] += x;
        __syncthreads();
    }
    int excl = (t > 0) ? sd[t - 1] : 0;
#pragma unroll
    for (int j = 0; j < 4; j++) {
        int i = base + t * 4 + j;
        if (i < NN) row_ptr[i] = excl + v[j];
    }
    if (t == 255) bsums[blockIdx.x] = sd[255];
}

// parallel single-block scan over nb<=128 block sums (was serial 1-thread loop)
static __global__ void k_scan2(int* __restrict__ bsums, int nb) {
    __shared__ int sd[128];
    int t = threadIdx.x;
    int v = (t < nb) ? bsums[t] : 0;
    sd[t] = v;
    __syncthreads();
    for (int off = 1; off < 128; off <<= 1) {
        int x = (t >= off) ? sd[t - off] : 0;
        __syncthreads();
        sd[t] += x;
        __syncthreads();
    }
    if (t < nb) bsums[t] = sd[t] - v;  // exclusive
}

static __global__ void k_scan3(int* __restrict__ row_ptr, const int* __restrict__ bsums) {
    int i = blockIdx.x * 256 + threadIdx.x;
    if (i < NN) {
        row_ptr[i] += bsums[i >> 10];
    } else if (i == NN) {
        row_ptr[NN] = NE;
    }
}

// per-bucket CSR fill: ranks via LDS atomics, csr writes confined to a 16KB
// L2-hot segment per block; 391 blocks x 16 waves -> ~24 waves/CU
static __global__ __launch_bounds__(1024) void k_bfill(const int2* __restrict__ staging,
                                                       const int* __restrict__ gbase,
                                                       const int* __restrict__ row_ptr,
                                                       int* __restrict__ csr_src) {
    __shared__ int cnt[256];
    int b = blockIdx.x;
    int t = threadIdx.x;
    if (t < 256) cnt[t] = 0;
    __syncthreads();
    int end = gbase[b + 1];
    for (int i = gbase[b] + t; i < end; i += 1024) {
        int2 ed = staging[i];
        int r = atomicAdd(&cnt[ed.y & 255], 1);
        csr_src[row_ptr[ed.y] + r] = ed.x;
    }
}

// ---------------- bf16 helpers ----------------
__device__ __forceinline__ void split_bf16(float f, short& hi, short& lo) {
    union { float f; uint32_t u; } x;
    x.f = f;
    uint32_t uh = x.u + 0x7FFFu + ((x.u >> 16) & 1u);
    hi = (short)(uh >> 16);
    union { uint32_t u; float f; } hf;
    hf.u = (uh >> 16) << 16;
    float r = f - hf.f;
    union { float f; uint32_t u; } y;
    y.f = r;
    uint32_t ul = y.u + 0x7FFFu + ((y.u >> 16) & 1u);
    lo = (short)(ul >> 16);
}

__device__ __forceinline__ u16 f2bf(float f) {  // RNE
    union { float f; uint32_t u; } x;
    x.f = f;
    uint32_t r = x.u + 0x7FFFu + ((x.u >> 16) & 1u);
    return (u16)(r >> 16);
}

__device__ __forceinline__ float bf2f(u16 h) {
    union { uint32_t u; float f; } x;
    x.u = ((uint32_t)h) << 16;
    return x.f;
}

// accumulate a packed pair of bf16 (low half -> a0, high half -> a1)
__device__ __forceinline__ void acc2(uint32_t u, float& a0, float& a1) {
    union { uint32_t u; float f; } lo, hi;
    lo.u = u << 16;
    hi.u = u & 0xFFFF0000u;
    a0 += lo.f;
    a1 += hi.f;
}

// ---------------- weight pre-split into MFMA B-fragment layout ----------------
struct WDesc {
    const float* W;
    short* fh;
    short* fl;
    int din, dout, transb, base, total;  // base/total in short8 groups
};
struct WPrepArgs { WDesc d[6]; };

static __global__ void k_wprep(WPrepArgs args) {
    int tid = blockIdx.x * 256 + threadIdx.x;
#pragma unroll
    for (int i = 0; i < 6; i++) {
        const WDesc& D = args.d[i];
        if (tid >= D.base && tid < D.base + D.total) {
            int local = tid - D.base;
            int lane = local & 63;
            int rest = local >> 6;
            int kst = D.din >> 5;
            int ks = rest % kst;
            int ntile = rest / kst;
            int n = ntile * 16 + (lane & 15);
            int k0 = ks * 32 + (lane >> 4) * 8;
#pragma unroll
            for (int j = 0; j < 8; j++) {
                int k = k0 + j;
                float v = D.transb ? D.W[(size_t)n * D.din + k]
                                   : D.W[(size_t)k * D.dout + n];
                short h, l;
                split_bf16(v, h, l);
                D.fh[(size_t)local * 8 + j] = h;
                D.fl[(size_t)local * 8 + j] = l;
            }
        }
    }
}

// ---------------- MFMA GEMM: LDS-free, B in registers, 2 N-tiles/wave ----------
// OBF16: emit bf16 (RNE) output — used for buffers consumed ONLY by k_agg,
// halving the random-gather bytes of the aggregation stage.
template <int DIN, int DOUT, bool RESID, bool BIAS, bool SCALE, bool OBF16>
__global__ __launch_bounds__(256) void k_mgemm(const float* __restrict__ A,
                                               const short* __restrict__ fh,
                                               const short* __restrict__ fl,
                                               const float* __restrict__ bias,
                                               const float* __restrict__ dinv,
                                               void* __restrict__ C) {
    static_assert(!RESID || DIN == DOUT, "residual needs square");
    constexpr int KST = DIN / 32;
    constexpr int NTW = DOUT / 64;  // N-tiles per wave (block: 4 waves = DOUT/16 tiles)
    const int t = threadIdx.x;
    const int wave = t >> 6;
    const int lane = t & 63;
    const int r16 = lane & 15;
    const int kq = lane >> 4;

    short8 bh[NTW][KST], bl[NTW][KST];
#pragma unroll
    for (int nt = 0; nt < NTW; nt++) {
        int ntile = wave * NTW + nt;
#pragma unroll
        for (int ks = 0; ks < KST; ks++) {
            size_t o = ((size_t)(ntile * KST + ks) * 64 + lane) * 8;
            bh[nt][ks] = *(const short8*)(fh + o);
            bl[nt][ks] = *(const short8*)(fl + o);
        }
    }

    const int m0b = blockIdx.x * 128;
#pragma unroll 1
    for (int mt = 0; mt < 8; mt++) {
        const int m0 = m0b + mt * 16;
        if (m0 >= NN) break;
        const int ra = min(m0 + r16, NN - 1);  // clamp; stores guarded
        const float* Ap = A + (size_t)ra * DIN + kq * 8;

        floatx4 acc[NTW];
#pragma unroll
        for (int nt = 0; nt < NTW; nt++) acc[nt] = (floatx4){0.f, 0.f, 0.f, 0.f};

#pragma unroll
        for (int ks = 0; ks < KST; ks++) {
            float4 f0 = *(const float4*)(Ap + ks * 32);
            float4 f1 = *(const float4*)(Ap + ks * 32 + 4);
            float fe[8] = {f0.x, f0.y, f0.z, f0.w, f1.x, f1.y, f1.z, f1.w};
            short8 ah, al;
#pragma unroll
            for (int j = 0; j < 8; j++) {
                short h, l;
                split_bf16(fe[j], h, l);
                ah[j] = h;
                al[j] = l;
            }
#pragma unroll
            for (int nt = 0; nt < NTW; nt++) {
                acc[nt] = __builtin_amdgcn_mfma_f32_16x16x32_bf16(ah, bh[nt][ks], acc[nt], 0, 0, 0);
                acc[nt] = __builtin_amdgcn_mfma_f32_16x16x32_bf16(ah, bl[nt][ks], acc[nt], 0, 0, 0);
                acc[nt] = __builtin_amdgcn_mfma_f32_16x16x32_bf16(al, bh[nt][ks], acc[nt], 0, 0, 0);
            }
        }

        // C/D layout: row = kq*4 + r, col = r16 (verified)
#pragma unroll
        for (int nt = 0; nt < NTW; nt++) {
            int col = (wave * NTW + nt) * 16 + r16;
#pragma unroll
            for (int r = 0; r < 4; r++) {
                int row = m0 + kq * 4 + r;
                if (row < NN) {
                    float v = acc[nt][r];
                    if constexpr (RESID) v = fmaxf(v + A[(size_t)row * DIN + col], 0.f);
                    if constexpr (BIAS)  v = fmaxf(v + bias[col], 0.f);
                    if constexpr (SCALE) v *= dinv[row];
                    if constexpr (OBF16)
                        ((u16*)C)[(size_t)row * DOUT + col] = f2bf(v);
                    else
                        ((float*)C)[(size_t)row * DOUT + col] = v;
                }
            }
        }
    }
}

// ---------------- GCN aggregation: bf16 gather payload, fp32 accumulate -------
template <int D, bool BIAS_RELU>
__global__ __launch_bounds__(256) void k_agg(const u16* __restrict__ hs,
                                             const float* __restrict__ dinv,
                                             const int* __restrict__ row_ptr,
                                             const int* __restrict__ csr_src,
                                             const float* __restrict__ bias,
                                             float* __restrict__ out) {
    constexpr int V = D / 64;
    int node = blockIdx.x * 4 + (threadIdx.x >> 6);
    int lane = threadIdx.x & 63;
    if (node >= NN) return;
    const int off = lane * V;

    float a0 = 0.f, a1 = 0.f;
    if constexpr (V == 2) {
        uint32_t u = ((const uint32_t*)(hs + (size_t)node * D))[lane];
        acc2(u, a0, a1);
    } else {
        a0 = bf2f(hs[(size_t)node * D + lane]);
    }

    int e = row_ptr[node];
    const int end = row_ptr[node + 1];

    for (; e + 8 <= end; e += 8) {
        int s[8];
#pragma unroll
        for (int i = 0; i < 8; i++) s[i] = csr_src[e + i];
        if constexpr (V == 2) {
            uint32_t v[8];
#pragma unroll
            for (int i = 0; i < 8; i++) v[i] = ((const uint32_t*)(hs + (size_t)s[i] * D))[lane];
#pragma unroll
            for (int i = 0; i < 8; i++) acc2(v[i], a0, a1);
        } else {
            u16 v[8];
#pragma unroll
            for (int i = 0; i < 8; i++) v[i] = hs[(size_t)s[i] * D + lane];
#pragma unroll
            for (int i = 0; i < 8; i++) a0 += bf2f(v[i]);
        }
    }
    for (; e + 4 <= end; e += 4) {
        int s[4];
#pragma unroll
        for (int i = 0; i < 4; i++) s[i] = csr_src[e + i];
        if constexpr (V == 2) {
            uint32_t v[4];
#pragma unroll
            for (int i = 0; i < 4; i++) v[i] = ((const uint32_t*)(hs + (size_t)s[i] * D))[lane];
#pragma unroll
            for (int i = 0; i < 4; i++) acc2(v[i], a0, a1);
        } else {
            u16 v[4];
#pragma unroll
            for (int i = 0; i < 4; i++) v[i] = hs[(size_t)s[i] * D + lane];
#pragma unroll
            for (int i = 0; i < 4; i++) a0 += bf2f(v[i]);
        }
    }
    for (; e < end; e++) {
        int s = csr_src[e];
        if constexpr (V == 2) {
            uint32_t u = ((const uint32_t*)(hs + (size_t)s * D))[lane];
            acc2(u, a0, a1);
        } else {
            a0 += bf2f(hs[(size_t)s * D + lane]);
        }
    }

    const float di = dinv[node];
    a0 *= di;
    if constexpr (V == 2) a1 *= di;
    if constexpr (BIAS_RELU) {
        a0 = fmaxf(a0 + bias[off], 0.f);
        if constexpr (V == 2) a1 = fmaxf(a1 + bias[off + 1], 0.f);
    }
    float* po = out + (size_t)node * D + off;
    if constexpr (V == 2) { *(float2*)po = make_float2(a0, a1); }
    else *po = a0;
}

// ---------------- launch ----------------

extern "C" void kernel_launch(void* const* d_in, const int* in_sizes, int n_in,
                              void* d_out, int out_size, void* d_ws, size_t ws_size,
                              hipStream_t stream) {
    const float* x   = (const float*)d_in[0];
    const int*   ei  = (const int*)d_in[1];
    const float* g1w = (const float*)d_in[2];
    const float* g1b = (const float*)d_in[3];
    const float* f2w = (const float*)d_in[4];
    const float* g3w = (const float*)d_in[5];
    const float* g3b = (const float*)d_in[6];
    const float* f4w = (const float*)d_in[7];
    const float* g5w = (const float*)d_in[8];
    const float* g5b = (const float*)d_in[9];
    const float* f6w = (const float*)d_in[10];
    float* out = (float*)d_out;

    const int* src = ei;       // edge_index[0]
    const int* dst = ei + NE;  // edge_index[1]

    char* p = (char*)d_ws;
    auto alloc = [&](size_t bytes) -> void* {
        void* r = (void*)p;
        p += (bytes + 255) & ~(size_t)255;
        return r;
    };
    int*   deg     = (int*)alloc(NN * 4);
    float* dinv    = (float*)alloc(NN * 4);
    int*   row_ptr = (int*)alloc((NN + 1) * 4);
    int*   bsums   = (int*)alloc(512);
    int*   gh      = (int*)alloc((NBB + 1) * 4);
    int*   gbase   = (int*)alloc((NBB + 1) * 4);
    int*   gcur    = (int*)alloc((NBB + 1) * 4);
    int*   csr     = (int*)alloc(NE * 4);
    short* wfh     = (short*)alloc(69632 * 2);
    short* wfl     = (short*)alloc(69632 * 2);
    float* bufA    = (float*)alloc((size_t)NN * 128 * 4);
    float* bufB    = (float*)alloc((size_t)NN * 128 * 4);
    // edge staging (12.8 MB) aliases bufB: fully consumed by k_blocal/k_bfill
    // before agg1 writes bufB (stream-ordered).
    int2* staging  = (int2*)bufB;

    const int gE4 = (NE + 4095) / 4096;      // 391
    const int gS  = (NN + 1023) / 1024;      // 98
    const int gN1 = (NN + 1 + 255) / 256;
    const int gA  = NN / 4;                  // 25000
    const int gM  = (NN + 127) / 128;        // 782

    // graph preprocessing
    k_zero<<<1, 512, 0, stream>>>(gh);
    k_bhist<<<gE4, 1024, 0, stream>>>(dst, gh);
    k_bscan<<<1, 512, 0, stream>>>(gh, gbase, gcur);
    k_bscatter<<<gE4, 1024, 0, stream>>>(src, dst, gcur, staging);
    k_blocal<<<NBB, 1024, 0, stream>>>(staging, gbase, deg, dinv);
    k_scan1<<<gS, 256, 0, stream>>>(deg, row_ptr, bsums);
    k_scan2<<<1, 128, 0, stream>>>(bsums, gS);
    k_scan3<<<gN1, 256, 0, stream>>>(row_ptr, bsums);
    k_bfill<<<NBB, 1024, 0, stream>>>(staging, gbase, row_ptr, csr);

    // weight fragment prep
    {
        WPrepArgs a;
        int  eoff[6] = {0, 16384, 32768, 40960, 45056, 53248};
        int  base[6] = {0, 2048, 4096, 5120, 5632, 6656};
        int  tot[6]  = {2048, 2048, 1024, 512, 1024, 2048};
        const float* Ws[6] = {g1w, f2w, g3w, f4w, g5w, f6w};
        int din[6]  = {128, 128, 128, 64, 64, 128};
        int dout[6] = {128, 128, 64, 64, 128, 128};
        int trb[6]  = {0, 1, 0, 1, 0, 1};
        for (int i = 0; i < 6; i++) {
            a.d[i] = WDesc{Ws[i], wfh + eoff[i], wfl + eoff[i],
                           din[i], dout[i], trb[i], base[i], tot[i]};
        }
        k_wprep<<<(8704 + 255) / 256, 256, 0, stream>>>(a);
    }

    // layer 1: hs1 = bf16(dinv*(x@W1)); z1 = relu(dinv*agg(hs1)+b1); z1' = relu(z1 + z1@fc2^T)
    k_mgemm<128, 128, false, false, true, true><<<gM, 256, 0, stream>>>(
        x, wfh + 0, wfl + 0, nullptr, dinv, bufA);
    k_agg<128, true><<<gA, 256, 0, stream>>>((const u16*)bufA, dinv, row_ptr, csr, g1b, bufB);
    k_mgemm<128, 128, true, false, false, false><<<gM, 256, 0, stream>>>(
        bufB, wfh + 16384, wfl + 16384, nullptr, nullptr, bufA);

    // layer 2
    k_mgemm<128, 64, false, false, true, true><<<gM, 256, 0, stream>>>(
        bufA, wfh + 32768, wfl + 32768, nullptr, dinv, bufB);
    k_agg<64, true><<<gA, 256, 0, stream>>>((const u16*)bufB, dinv, row_ptr, csr, g3b, bufA);
    k_mgemm<64, 64, true, false, true, true><<<gM, 256, 0, stream>>>(
        bufA, wfh + 40960, wfl + 40960, nullptr, dinv, bufB);

    // layer 3 (reordered: aggregate at 64ch, then GEMM)
    k_agg<64, false><<<gA, 256, 0, stream>>>((const u16*)bufB, dinv, row_ptr, csr, nullptr, bufA);
    k_mgemm<64, 128, false, true, false, false><<<gM, 256, 0, stream>>>(
        bufA, wfh + 45056, wfl + 45056, g5b, nullptr, bufB);
    k_mgemm<128, 128, true, false, false, false><<<gM, 256, 0, stream>>>(
        bufB, wfh + 53248, wfl + 53248, nullptr, nullptr, out);
}

// Round 2
// 572.991 us; speedup vs baseline: 1.2380x; 1.0639x over previous
//
#include <hip/hip_runtime.h>
#include <cstdint>
#include <cstddef>

#define NN 100000
#define NE 1600000
#define NBB 391   // dst buckets of 256 nodes: ceil(100000/256)

typedef short short8 __attribute__((ext_vector_type(8)));
typedef float floatx4 __attribute__((ext_vector_type(4)));
typedef unsigned short u16;

// ---------------- graph preprocessing (bucketed, atomic-light) ----------------

static __global__ void k_zero(int* __restrict__ gh) {
    int i = threadIdx.x;
    if (i < NBB + 1) gh[i] = 0;
}

// histogram of dst>>8 ; 1024 thr x 4 edges/block -> 391 global atomics/block
static __global__ __launch_bounds__(1024) void k_bhist(const int* __restrict__ dst,
                                                       int* __restrict__ gh) {
    __shared__ int h[NBB + 1];
    int t = threadIdx.x;
    for (int i = t; i < NBB; i += 1024) h[i] = 0;
    __syncthreads();
    int e0 = blockIdx.x * 4096;
#pragma unroll
    for (int j = 0; j < 4; j++) {
        int e = e0 + j * 1024 + t;
        if (e < NE) atomicAdd(&h[dst[e] >> 8], 1);
    }
    __syncthreads();
    for (int i = t; i < NBB; i += 1024)
        if (h[i]) atomicAdd(&gh[i], h[i]);
}

// parallel single-block scan over NBB=391 bucket counts
static __global__ void k_bscan(const int* __restrict__ gh, int* __restrict__ gbase,
                               int* __restrict__ gcur) {
    __shared__ int sd[512];
    int t = threadIdx.x;
    int v = (t < NBB) ? gh[t] : 0;
    sd[t] = v;
    __syncthreads();
    for (int off = 1; off < 512; off <<= 1) {
        int x = (t >= off) ? sd[t - off] : 0;
        __syncthreads();
        sd[t] += x;
        __syncthreads();
    }
    int excl = (t > 0) ? sd[t - 1] : 0;
    if (t < NBB) {
        gbase[t] = excl;
        gcur[t] = excl;
    }
    if (t == NBB) gbase[NBB] = excl;  // == NE
}

// scatter edges into bucket-ordered staging (int2 = src,dst)
static __global__ __launch_bounds__(1024) void k_bscatter(const int* __restrict__ src,
                                                          const int* __restrict__ dst,
                                                          int* __restrict__ gcur,
                                                          int2* __restrict__ staging) {
    __shared__ int h[NBB + 1];
    __shared__ int base[NBB + 1];
    int t = threadIdx.x;
    for (int i = t; i < NBB; i += 1024) h[i] = 0;
    __syncthreads();
    int e0 = blockIdx.x * 4096;
    int b[4], l[4], sv[4], dv[4];
#pragma unroll
    for (int j = 0; j < 4; j++) {
        int e = e0 + j * 1024 + t;
        b[j] = -1;
        if (e < NE) {
            sv[j] = src[e];
            dv[j] = dst[e];
            b[j] = dv[j] >> 8;
            l[j] = atomicAdd(&h[b[j]], 1);
        }
    }
    __syncthreads();
    for (int i = t; i < NBB; i += 1024)
        if (h[i]) base[i] = atomicAdd(&gcur[i], h[i]);
    __syncthreads();
#pragma unroll
    for (int j = 0; j < 4; j++)
        if (b[j] >= 0) staging[base[b[j]] + l[j]] = make_int2(sv[j], dv[j]);
}

// per-bucket degree count via LDS -> deg/dinv written coalesced, no global atomics
static __global__ __launch_bounds__(1024) void k_blocal(const int2* __restrict__ staging,
                                                        const int* __restrict__ gbase,
                                                        int* __restrict__ deg,
                                                        float* __restrict__ dinv) {
    __shared__ int cnt[256];
    int b = blockIdx.x;
    int t = threadIdx.x;
    if (t < 256) cnt[t] = 0;
    __syncthreads();
    int end = gbase[b + 1];
    for (int i = gbase[b] + t; i < end; i += 1024)
        atomicAdd(&cnt[staging[i].y & 255], 1);
    __syncthreads();
    if (t < 256) {
        int node = (b << 8) + t;
        if (node < NN) {
            int d = cnt[t] + 1;  // +1 self loop
            deg[node] = d;
            dinv[node] = rsqrtf((float)d);
        }
    }
}

// exclusive scan of (deg[i]-1) -> row_ptr, chunk=1024/block
static __global__ void k_scan1(const int* __restrict__ deg, int* __restrict__ row_ptr,
                               int* __restrict__ bsums) {
    __shared__ int sd[256];
    int t = threadIdx.x;
    int base = blockIdx.x * 1024;
    int v[4];
    int s = 0;
#pragma unroll
    for (int j = 0; j < 4; j++) {
        int i = base + t * 4 + j;
        int c = (i < NN) ? (deg[i] - 1) : 0;
        v[j] = s;
        s += c;
    }
    sd[t] = s;
    __syncthreads();
    for (int off = 1; off < 256; off <<= 1) {
        int x = (t >= off) ? sd[t - off] : 0;
        __syncthreads();
        sd[t] += x;
        __syncthreads();
    }
    int excl = (t > 0) ? sd[t - 1] : 0;
#pragma unroll
    for (int j = 0; j < 4; j++) {
        int i = base + t * 4 + j;
        if (i < NN) row_ptr[i] = excl + v[j];
    }
    if (t == 255) bsums[blockIdx.x] = sd[255];
}

// parallel single-block scan over nb<=128 block sums
static __global__ void k_scan2(int* __restrict__ bsums, int nb) {
    __shared__ int sd[128];
    int t = threadIdx.x;
    int v = (t < nb) ? bsums[t] : 0;
    sd[t] = v;
    __syncthreads();
    for (int off = 1; off < 128; off <<= 1) {
        int x = (t >= off) ? sd[t - off] : 0;
        __syncthreads();
        sd[t] += x;
        __syncthreads();
    }
    if (t < nb) bsums[t] = sd[t] - v;  // exclusive
}

static __global__ void k_scan3(int* __restrict__ row_ptr, const int* __restrict__ bsums) {
    int i = blockIdx.x * 256 + threadIdx.x;
    if (i < NN) {
        row_ptr[i] += bsums[i >> 10];
    } else if (i == NN) {
        row_ptr[NN] = NE;
    }
}

// per-bucket CSR fill: ranks via LDS atomics
static __global__ __launch_bounds__(1024) void k_bfill(const int2* __restrict__ staging,
                                                       const int* __restrict__ gbase,
                                                       const int* __restrict__ row_ptr,
                                                       int* __restrict__ csr_src) {
    __shared__ int cnt[256];
    int b = blockIdx.x;
    int t = threadIdx.x;
    if (t < 256) cnt[t] = 0;
    __syncthreads();
    int end = gbase[b + 1];
    for (int i = gbase[b] + t; i < end; i += 1024) {
        int2 ed = staging[i];
        int r = atomicAdd(&cnt[ed.y & 255], 1);
        csr_src[row_ptr[ed.y] + r] = ed.x;
    }
}

// ---------------- bf16 helpers ----------------
__device__ __forceinline__ void split_bf16(float f, short& hi, short& lo) {
    union { float f; uint32_t u; } x;
    x.f = f;
    uint32_t uh = x.u + 0x7FFFu + ((x.u >> 16) & 1u);
    hi = (short)(uh >> 16);
    union { uint32_t u; float f; } hf;
    hf.u = (uh >> 16) << 16;
    float r = f - hf.f;
    union { float f; uint32_t u; } y;
    y.f = r;
    uint32_t ul = y.u + 0x7FFFu + ((y.u >> 16) & 1u);
    lo = (short)(ul >> 16);
}

__device__ __forceinline__ u16 f2bf(float f) {  // RNE
    union { float f; uint32_t u; } x;
    x.f = f;
    uint32_t r = x.u + 0x7FFFu + ((x.u >> 16) & 1u);
    return (u16)(r >> 16);
}

__device__ __forceinline__ float bf2f(u16 h) {
    union { uint32_t u; float f; } x;
    x.u = ((uint32_t)h) << 16;
    return x.f;
}

// accumulate a packed pair of bf16 (low half -> a0, high half -> a1)
__device__ __forceinline__ void acc2(uint32_t u, float& a0, float& a1) {
    union { uint32_t u; float f; } lo, hi;
    lo.u = u << 16;
    hi.u = u & 0xFFFF0000u;
    a0 += lo.f;
    a1 += hi.f;
}

// ---------------- weight pre-split into MFMA B-fragment layout ----------------
struct WDesc {
    const float* W;
    short* fh;
    short* fl;
    int din, dout, transb, base, total;  // base/total in short8 groups
};
struct WPrepArgs { WDesc d[6]; };

static __global__ void k_wprep(WPrepArgs args) {
    int tid = blockIdx.x * 256 + threadIdx.x;
#pragma unroll
    for (int i = 0; i < 6; i++) {
        const WDesc& D = args.d[i];
        if (tid >= D.base && tid < D.base + D.total) {
            int local = tid - D.base;
            int lane = local & 63;
            int rest = local >> 6;
            int kst = D.din >> 5;
            int ks = rest % kst;
            int ntile = rest / kst;
            int n = ntile * 16 + (lane & 15);
            int k0 = ks * 32 + (lane >> 4) * 8;
#pragma unroll
            for (int j = 0; j < 8; j++) {
                int k = k0 + j;
                float v = D.transb ? D.W[(size_t)n * D.din + k]
                                   : D.W[(size_t)k * D.dout + n];
                short h, l;
                split_bf16(v, h, l);
                D.fh[(size_t)local * 8 + j] = h;
                D.fl[(size_t)local * 8 + j] = l;
            }
        }
    }
}

// ---------------- MFMA GEMM: LDS-free, B in registers ------------------------
// Round-1 lesson: 8 m-tiles/block serial loop -> 782 blocks -> Occupancy 21%,
// MfmaUtil 4.5%, hbm 8%: latency-bound on the load->split->MFMA chain.
// MT m-tiles/block (MT=2): 3125 blocks (100000 = 3125*32, no tail) -> ~49
// waves/CU demanded, VGPR-68 caps ~28/CU -> TLP hides latency. B-fragment
// reload cost: 64KB x 3125 blocks ~ 200MB L2 reads over ~15us = 13 TB/s,
// well under the 34.5 TB/s L2 ceiling.
template <int DIN, int DOUT, int MT, bool RESID, bool BIAS, bool SCALE, bool OBF16>
__global__ __launch_bounds__(256) void k_mgemm(const float* __restrict__ A,
                                               const short* __restrict__ fh,
                                               const short* __restrict__ fl,
                                               const float* __restrict__ bias,
                                               const float* __restrict__ dinv,
                                               void* __restrict__ C) {
    static_assert(!RESID || DIN == DOUT, "residual needs square");
    constexpr int KST = DIN / 32;
    constexpr int NTW = DOUT / 64;  // N-tiles per wave (block: 4 waves = DOUT/16 tiles)
    const int t = threadIdx.x;
    const int wave = t >> 6;
    const int lane = t & 63;
    const int r16 = lane & 15;
    const int kq = lane >> 4;

    short8 bh[NTW][KST], bl[NTW][KST];
#pragma unroll
    for (int nt = 0; nt < NTW; nt++) {
        int ntile = wave * NTW + nt;
#pragma unroll
        for (int ks = 0; ks < KST; ks++) {
            size_t o = ((size_t)(ntile * KST + ks) * 64 + lane) * 8;
            bh[nt][ks] = *(const short8*)(fh + o);
            bl[nt][ks] = *(const short8*)(fl + o);
        }
    }

    const int m0b = blockIdx.x * (MT * 16);
#pragma unroll 1
    for (int mt = 0; mt < MT; mt++) {
        const int m0 = m0b + mt * 16;
        if (m0 >= NN) break;
        const int ra = min(m0 + r16, NN - 1);  // clamp; stores guarded
        const float* Ap = A + (size_t)ra * DIN + kq * 8;

        floatx4 acc[NTW];
#pragma unroll
        for (int nt = 0; nt < NTW; nt++) acc[nt] = (floatx4){0.f, 0.f, 0.f, 0.f};

#pragma unroll
        for (int ks = 0; ks < KST; ks++) {
            float4 f0 = *(const float4*)(Ap + ks * 32);
            float4 f1 = *(const float4*)(Ap + ks * 32 + 4);
            float fe[8] = {f0.x, f0.y, f0.z, f0.w, f1.x, f1.y, f1.z, f1.w};
            short8 ah, al;
#pragma unroll
            for (int j = 0; j < 8; j++) {
                short h, l;
                split_bf16(fe[j], h, l);
                ah[j] = h;
                al[j] = l;
            }
#pragma unroll
            for (int nt = 0; nt < NTW; nt++) {
                acc[nt] = __builtin_amdgcn_mfma_f32_16x16x32_bf16(ah, bh[nt][ks], acc[nt], 0, 0, 0);
                acc[nt] = __builtin_amdgcn_mfma_f32_16x16x32_bf16(ah, bl[nt][ks], acc[nt], 0, 0, 0);
                acc[nt] = __builtin_amdgcn_mfma_f32_16x16x32_bf16(al, bh[nt][ks], acc[nt], 0, 0, 0);
            }
        }

        // C/D layout: row = kq*4 + r, col = r16 (verified)
#pragma unroll
        for (int nt = 0; nt < NTW; nt++) {
            int col = (wave * NTW + nt) * 16 + r16;
#pragma unroll
            for (int r = 0; r < 4; r++) {
                int row = m0 + kq * 4 + r;
                if (row < NN) {
                    float v = acc[nt][r];
                    if constexpr (RESID) v = fmaxf(v + A[(size_t)row * DIN + col], 0.f);
                    if constexpr (BIAS)  v = fmaxf(v + bias[col], 0.f);
                    if constexpr (SCALE) v *= dinv[row];
                    if constexpr (OBF16)
                        ((u16*)C)[(size_t)row * DOUT + col] = f2bf(v);
                    else
                        ((float*)C)[(size_t)row * DOUT + col] = v;
                }
            }
        }
    }
}

// ---------------- GCN aggregation: bf16 gather payload, fp32 accumulate -------
template <int D, bool BIAS_RELU>
__global__ __launch_bounds__(256) void k_agg(const u16* __restrict__ hs,
                                             const float* __restrict__ dinv,
                                             const int* __restrict__ row_ptr,
                                             const int* __restrict__ csr_src,
                                             const float* __restrict__ bias,
                                             float* __restrict__ out) {
    constexpr int V = D / 64;
    int node = blockIdx.x * 4 + (threadIdx.x >> 6);
    int lane = threadIdx.x & 63;
    if (node >= NN) return;
    const int off = lane * V;

    float a0 = 0.f, a1 = 0.f;
    if constexpr (V == 2) {
        uint32_t u = ((const uint32_t*)(hs + (size_t)node * D))[lane];
        acc2(u, a0, a1);
    } else {
        a0 = bf2f(hs[(size_t)node * D + lane]);
    }

    int e = row_ptr[node];
    const int end = row_ptr[node + 1];

    for (; e + 8 <= end; e += 8) {
        int s[8];
#pragma unroll
        for (int i = 0; i < 8; i++) s[i] = csr_src[e + i];
        if constexpr (V == 2) {
            uint32_t v[8];
#pragma unroll
            for (int i = 0; i < 8; i++) v[i] = ((const uint32_t*)(hs + (size_t)s[i] * D))[lane];
#pragma unroll
            for (int i = 0; i < 8; i++) acc2(v[i], a0, a1);
        } else {
            u16 v[8];
#pragma unroll
            for (int i = 0; i < 8; i++) v[i] = hs[(size_t)s[i] * D + lane];
#pragma unroll
            for (int i = 0; i < 8; i++) a0 += bf2f(v[i]);
        }
    }
    for (; e + 4 <= end; e += 4) {
        int s[4];
#pragma unroll
        for (int i = 0; i < 4; i++) s[i] = csr_src[e + i];
        if constexpr (V == 2) {
            uint32_t v[4];
#pragma unroll
            for (int i = 0; i < 4; i++) v[i] = ((const uint32_t*)(hs + (size_t)s[i] * D))[lane];
#pragma unroll
            for (int i = 0; i < 4; i++) acc2(v[i], a0, a1);
        } else {
            u16 v[4];
#pragma unroll
            for (int i = 0; i < 4; i++) v[i] = hs[(size_t)s[i] * D + lane];
#pragma unroll
            for (int i = 0; i < 4; i++) a0 += bf2f(v[i]);
        }
    }
    for (; e < end; e++) {
        int s = csr_src[e];
        if constexpr (V == 2) {
            uint32_t u = ((const uint32_t*)(hs + (size_t)s * D))[lane];
            acc2(u, a0, a1);
        } else {
            a0 += bf2f(hs[(size_t)s * D + lane]);
        }
    }

    const float di = dinv[node];
    a0 *= di;
    if constexpr (V == 2) a1 *= di;
    if constexpr (BIAS_RELU) {
        a0 = fmaxf(a0 + bias[off], 0.f);
        if constexpr (V == 2) a1 = fmaxf(a1 + bias[off + 1], 0.f);
    }
    float* po = out + (size_t)node * D + off;
    if constexpr (V == 2) { *(float2*)po = make_float2(a0, a1); }
    else *po = a0;
}

// ---------------- launch ----------------

extern "C" void kernel_launch(void* const* d_in, const int* in_sizes, int n_in,
                              void* d_out, int out_size, void* d_ws, size_t ws_size,
                              hipStream_t stream) {
    const float* x   = (const float*)d_in[0];
    const int*   ei  = (const int*)d_in[1];
    const float* g1w = (const float*)d_in[2];
    const float* g1b = (const float*)d_in[3];
    const float* f2w = (const float*)d_in[4];
    const float* g3w = (const float*)d_in[5];
    const float* g3b = (const float*)d_in[6];
    const float* f4w = (const float*)d_in[7];
    const float* g5w = (const float*)d_in[8];
    const float* g5b = (const float*)d_in[9];
    const float* f6w = (const float*)d_in[10];
    float* out = (float*)d_out;

    const int* src = ei;       // edge_index[0]
    const int* dst = ei + NE;  // edge_index[1]

    char* p = (char*)d_ws;
    auto alloc = [&](size_t bytes) -> void* {
        void* r = (void*)p;
        p += (bytes + 255) & ~(size_t)255;
        return r;
    };
    int*   deg     = (int*)alloc(NN * 4);
    float* dinv    = (float*)alloc(NN * 4);
    int*   row_ptr = (int*)alloc((NN + 1) * 4);
    int*   bsums   = (int*)alloc(512);
    int*   gh      = (int*)alloc((NBB + 1) * 4);
    int*   gbase   = (int*)alloc((NBB + 1) * 4);
    int*   gcur    = (int*)alloc((NBB + 1) * 4);
    int*   csr     = (int*)alloc(NE * 4);
    short* wfh     = (short*)alloc(69632 * 2);
    short* wfl     = (short*)alloc(69632 * 2);
    float* bufA    = (float*)alloc((size_t)NN * 128 * 4);
    float* bufB    = (float*)alloc((size_t)NN * 128 * 4);
    // edge staging (12.8 MB) aliases bufB: fully consumed by k_blocal/k_bfill
    // before agg1 writes bufB (stream-ordered).
    int2* staging  = (int2*)bufB;

    const int gE4 = (NE + 4095) / 4096;      // 391
    const int gS  = (NN + 1023) / 1024;      // 98
    const int gN1 = (NN + 1 + 255) / 256;
    const int gA  = NN / 4;                  // 25000
    const int gM  = (NN + 31) / 32;          // 3125 (MT=2: 32 rows/block, exact)

    // graph preprocessing
    k_zero<<<1, 512, 0, stream>>>(gh);
    k_bhist<<<gE4, 1024, 0, stream>>>(dst, gh);
    k_bscan<<<1, 512, 0, stream>>>(gh, gbase, gcur);
    k_bscatter<<<gE4, 1024, 0, stream>>>(src, dst, gcur, staging);
    k_blocal<<<NBB, 1024, 0, stream>>>(staging, gbase, deg, dinv);
    k_scan1<<<gS, 256, 0, stream>>>(deg, row_ptr, bsums);
    k_scan2<<<1, 128, 0, stream>>>(bsums, gS);
    k_scan3<<<gN1, 256, 0, stream>>>(row_ptr, bsums);
    k_bfill<<<NBB, 1024, 0, stream>>>(staging, gbase, row_ptr, csr);

    // weight fragment prep
    {
        WPrepArgs a;
        int  eoff[6] = {0, 16384, 32768, 40960, 45056, 53248};
        int  base[6] = {0, 2048, 4096, 5120, 5632, 6656};
        int  tot[6]  = {2048, 2048, 1024, 512, 1024, 2048};
        const float* Ws[6] = {g1w, f2w, g3w, f4w, g5w, f6w};
        int din[6]  = {128, 128, 128, 64, 64, 128};
        int dout[6] = {128, 128, 64, 64, 128, 128};
        int trb[6]  = {0, 1, 0, 1, 0, 1};
        for (int i = 0; i < 6; i++) {
            a.d[i] = WDesc{Ws[i], wfh + eoff[i], wfl + eoff[i],
                           din[i], dout[i], trb[i], base[i], tot[i]};
        }
        k_wprep<<<(8704 + 255) / 256, 256, 0, stream>>>(a);
    }

    // layer 1: hs1 = bf16(dinv*(x@W1)); z1 = relu(dinv*agg(hs1)+b1); z1' = relu(z1 + z1@fc2^T)
    k_mgemm<128, 128, 2, false, false, true, true><<<gM, 256, 0, stream>>>(
        x, wfh + 0, wfl + 0, nullptr, dinv, bufA);
    k_agg<128, true><<<gA, 256, 0, stream>>>((const u16*)bufA, dinv, row_ptr, csr, g1b, bufB);
    k_mgemm<128, 128, 2, true, false, false, false><<<gM, 256, 0, stream>>>(
        bufB, wfh + 16384, wfl + 16384, nullptr, nullptr, bufA);

    // layer 2
    k_mgemm<128, 64, 2, false, false, true, true><<<gM, 256, 0, stream>>>(
        bufA, wfh + 32768, wfl + 32768, nullptr, dinv, bufB);
    k_agg<64, true><<<gA, 256, 0, stream>>>((const u16*)bufB, dinv, row_ptr, csr, g3b, bufA);
    k_mgemm<64, 64, 2, true, false, true, true><<<gM, 256, 0, stream>>>(
        bufA, wfh + 40960, wfl + 40960, nullptr, dinv, bufB);

    // layer 3 (reordered: aggregate at 64ch, then GEMM)
    k_agg<64, false><<<gA, 256, 0, stream>>>((const u16*)bufB, dinv, row_ptr, csr, nullptr, bufA);
    k_mgemm<64, 128, 2, false, true, false, false><<<gM, 256, 0, stream>>>(
        bufA, wfh + 45056, wfl + 45056, g5b, nullptr, bufB);
    k_mgemm<128, 128, 2, true, false, false, false><<<gM, 256, 0, stream>>>(
        bufB, wfh + 53248, wfl + 53248, nullptr, nullptr, out);
}

// Round 3
// 555.155 us; speedup vs baseline: 1.2778x; 1.0321x over previous
//
#include <hip/hip_runtime.h>
#include <cstdint>
#include <cstddef>

#define NN 100000
#define NE 1600000
#define NBB 391   // dst buckets of 256 nodes: ceil(100000/256)

typedef short short8 __attribute__((ext_vector_type(8)));
typedef float floatx4 __attribute__((ext_vector_type(4)));
typedef uint32_t u32x4 __attribute__((ext_vector_type(4)));
typedef unsigned short u16;
typedef uint32_t u32;

// ---------------- graph preprocessing (bucketed, atomic-light) ----------------

static __global__ void k_zero(int* __restrict__ gh) {
    int i = threadIdx.x;
    if (i < NBB + 1) gh[i] = 0;
}

// histogram of dst>>8 ; 1024 thr x 4 edges/block -> 391 global atomics/block
static __global__ __launch_bounds__(1024) void k_bhist(const int* __restrict__ dst,
                                                       int* __restrict__ gh) {
    __shared__ int h[NBB + 1];
    int t = threadIdx.x;
    for (int i = t; i < NBB; i += 1024) h[i] = 0;
    __syncthreads();
    int e0 = blockIdx.x * 4096;
#pragma unroll
    for (int j = 0; j < 4; j++) {
        int e = e0 + j * 1024 + t;
        if (e < NE) atomicAdd(&h[dst[e] >> 8], 1);
    }
    __syncthreads();
    for (int i = t; i < NBB; i += 1024)
        if (h[i]) atomicAdd(&gh[i], h[i]);
}

// parallel single-block scan over NBB=391 bucket counts
static __global__ void k_bscan(const int* __restrict__ gh, int* __restrict__ gbase,
                               int* __restrict__ gcur) {
    __shared__ int sd[512];
    int t = threadIdx.x;
    int v = (t < NBB) ? gh[t] : 0;
    sd[t] = v;
    __syncthreads();
    for (int off = 1; off < 512; off <<= 1) {
        int x = (t >= off) ? sd[t - off] : 0;
        __syncthreads();
        sd[t] += x;
        __syncthreads();
    }
    int excl = (t > 0) ? sd[t - 1] : 0;
    if (t < NBB) {
        gbase[t] = excl;
        gcur[t] = excl;
    }
    if (t == NBB) gbase[NBB] = excl;  // == NE
}

// scatter edges into bucket-ordered staging (int2 = src,dst)
static __global__ __launch_bounds__(1024) void k_bscatter(const int* __restrict__ src,
                                                          const int* __restrict__ dst,
                                                          int* __restrict__ gcur,
                                                          int2* __restrict__ staging) {
    __shared__ int h[NBB + 1];
    __shared__ int base[NBB + 1];
    int t = threadIdx.x;
    for (int i = t; i < NBB; i += 1024) h[i] = 0;
    __syncthreads();
    int e0 = blockIdx.x * 4096;
    int b[4], l[4], sv[4], dv[4];
#pragma unroll
    for (int j = 0; j < 4; j++) {
        int e = e0 + j * 1024 + t;
        b[j] = -1;
        if (e < NE) {
            sv[j] = src[e];
            dv[j] = dst[e];
            b[j] = dv[j] >> 8;
            l[j] = atomicAdd(&h[b[j]], 1);
        }
    }
    __syncthreads();
    for (int i = t; i < NBB; i += 1024)
        if (h[i]) base[i] = atomicAdd(&gcur[i], h[i]);
    __syncthreads();
#pragma unroll
    for (int j = 0; j < 4; j++)
        if (b[j] >= 0) staging[base[b[j]] + l[j]] = make_int2(sv[j], dv[j]);
}

// per-bucket degree count via LDS -> deg/dinv written coalesced, no global atomics
static __global__ __launch_bounds__(1024) void k_blocal(const int2* __restrict__ staging,
                                                        const int* __restrict__ gbase,
                                                        int* __restrict__ deg,
                                                        float* __restrict__ dinv) {
    __shared__ int cnt[256];
    int b = blockIdx.x;
    int t = threadIdx.x;
    if (t < 256) cnt[t] = 0;
    __syncthreads();
    int end = gbase[b + 1];
    for (int i = gbase[b] + t; i < end; i += 1024)
        atomicAdd(&cnt[staging[i].y & 255], 1);
    __syncthreads();
    if (t < 256) {
        int node = (b << 8) + t;
        if (node < NN) {
            int d = cnt[t] + 1;  // +1 self loop
            deg[node] = d;
            dinv[node] = rsqrtf((float)d);
        }
    }
}

// exclusive scan of (deg[i]-1) -> row_ptr, chunk=1024/block
static __global__ void k_scan1(const int* __restrict__ deg, int* __restrict__ row_ptr,
                               int* __restrict__ bsums) {
    __shared__ int sd[256];
    int t = threadIdx.x;
    int base = blockIdx.x * 1024;
    int v[4];
    int s = 0;
#pragma unroll
    for (int j = 0; j < 4; j++) {
        int i = base + t * 4 + j;
        int c = (i < NN) ? (deg[i] - 1) : 0;
        v[j] = s;
        s += c;
    }
    sd[t] = s;
    __syncthreads();
    for (int off = 1; off < 256; off <<= 1) {
        int x = (t >= off) ? sd[t - off] : 0;
        __syncthreads();
        sd[t] += x;
        __syncthreads();
    }
    int excl = (t > 0) ? sd[t - 1] : 0;
#pragma unroll
    for (int j = 0; j < 4; j++) {
        int i = base + t * 4 + j;
        if (i < NN) row_ptr[i] = excl + v[j];
    }
    if (t == 255) bsums[blockIdx.x] = sd[255];
}

// parallel single-block scan over nb<=128 block sums
static __global__ void k_scan2(int* __restrict__ bsums, int nb) {
    __shared__ int sd[128];
    int t = threadIdx.x;
    int v = (t < nb) ? bsums[t] : 0;
    sd[t] = v;
    __syncthreads();
    for (int off = 1; off < 128; off <<= 1) {
        int x = (t >= off) ? sd[t - off] : 0;
        __syncthreads();
        sd[t] += x;
        __syncthreads();
    }
    if (t < nb) bsums[t] = sd[t] - v;  // exclusive
}

static __global__ void k_scan3(int* __restrict__ row_ptr, const int* __restrict__ bsums) {
    int i = blockIdx.x * 256 + threadIdx.x;
    if (i < NN) {
        row_ptr[i] += bsums[i >> 10];
    } else if (i == NN) {
        row_ptr[NN] = NE;
    }
}

// per-bucket CSR fill: ranks via LDS atomics
static __global__ __launch_bounds__(1024) void k_bfill(const int2* __restrict__ staging,
                                                       const int* __restrict__ gbase,
                                                       const int* __restrict__ row_ptr,
                                                       int* __restrict__ csr_src) {
    __shared__ int cnt[256];
    int b = blockIdx.x;
    int t = threadIdx.x;
    if (t < 256) cnt[t] = 0;
    __syncthreads();
    int end = gbase[b + 1];
    for (int i = gbase[b] + t; i < end; i += 1024) {
        int2 ed = staging[i];
        int r = atomicAdd(&cnt[ed.y & 255], 1);
        csr_src[row_ptr[ed.y] + r] = ed.x;
    }
}

// ---------------- bf16 helpers ----------------
__device__ __forceinline__ void split_bf16(float f, short& hi, short& lo) {
    union { float f; uint32_t u; } x;
    x.f = f;
    uint32_t uh = x.u + 0x7FFFu + ((x.u >> 16) & 1u);
    hi = (short)(uh >> 16);
    union { uint32_t u; float f; } hf;
    hf.u = (uh >> 16) << 16;
    float r = f - hf.f;
    union { float f; uint32_t u; } y;
    y.f = r;
    uint32_t ul = y.u + 0x7FFFu + ((y.u >> 16) & 1u);
    lo = (short)(ul >> 16);
}

__device__ __forceinline__ u16 f2bf(float f) {  // RNE
    union { float f; uint32_t u; } x;
    x.f = f;
    uint32_t r = x.u + 0x7FFFu + ((x.u >> 16) & 1u);
    return (u16)(r >> 16);
}

__device__ __forceinline__ float bf2f(u16 h) {
    union { uint32_t u; float f; } x;
    x.u = ((uint32_t)h) << 16;
    return x.f;
}

// packed split-bf16: low 16 = hi part, high 16 = lo part. hi+lo ~ fp32 (2^-16)
__device__ __forceinline__ u32 packsplit(float f) {
    short h, l;
    split_bf16(f, h, l);
    return (u32)(u16)h | ((u32)(u16)l << 16);
}

__device__ __forceinline__ float unpacksplit(u32 u) {
    return bf2f((u16)(u & 0xFFFFu)) + bf2f((u16)(u >> 16));
}

// accumulate a packed pair of bf16 (low half -> a0, high half -> a1)
__device__ __forceinline__ void acc2(uint32_t u, float& a0, float& a1) {
    union { uint32_t u; float f; } lo, hi;
    lo.u = u << 16;
    hi.u = u & 0xFFFF0000u;
    a0 += lo.f;
    a1 += hi.f;
}

// ---------------- weight pre-split into MFMA B-fragment layout ----------------
struct WDesc {
    const float* W;
    short* fh;
    short* fl;
    int din, dout, transb, base, total;  // base/total in short8 groups
};
struct WPrepArgs { WDesc d[6]; };

static __global__ void k_wprep(WPrepArgs args) {
    int tid = blockIdx.x * 256 + threadIdx.x;
#pragma unroll
    for (int i = 0; i < 6; i++) {
        const WDesc& D = args.d[i];
        if (tid >= D.base && tid < D.base + D.total) {
            int local = tid - D.base;
            int lane = local & 63;
            int rest = local >> 6;
            int kst = D.din >> 5;
            int ks = rest % kst;
            int ntile = rest / kst;
            int n = ntile * 16 + (lane & 15);
            int k0 = ks * 32 + (lane >> 4) * 8;
#pragma unroll
            for (int j = 0; j < 8; j++) {
                int k = k0 + j;
                float v = D.transb ? D.W[(size_t)n * D.din + k]
                                   : D.W[(size_t)k * D.dout + n];
                short h, l;
                split_bf16(v, h, l);
                D.fh[(size_t)local * 8 + j] = h;
                D.fl[(size_t)local * 8 + j] = l;
            }
        }
    }
}

// ---------------- MFMA GEMM: LDS-free, B in registers ------------------------
// Round-2 lesson: the in-GEMM fp32->split_bf16 chain (load -> ~100 VALU, 6-op
// serial per elem -> MFMA) was the latency bottleneck (MfmaUtil 4.5%, VALU 15%,
// hbm 8%: nothing saturated). Activations are now stored PRE-SPLIT as packed
// u32 (hi|lo<<16) by the producer kernels; A-frag load = 2x u32x4 + 16 bitops.
// AMODE: 1 = fp32 input, single-bf16 RNE (2 MFMAs) - only for G1 (x), whose
//            output is payload-rounded to bf16 anyway.
//        2 = packed split input (3 MFMAs, lossless vs fp32 to 2^-16)
// OMODE: 0 = fp32 out, 1 = single bf16 out (agg gather payload), 2 = packed out
template <int DIN, int DOUT, int MT, int AMODE, int OMODE, bool RESID, bool BIAS, bool SCALE>
__global__ __launch_bounds__(256) void k_mgemm(const void* __restrict__ Av,
                                               const short* __restrict__ fh,
                                               const short* __restrict__ fl,
                                               const float* __restrict__ bias,
                                               const float* __restrict__ dinv,
                                               void* __restrict__ C) {
    static_assert(!RESID || DIN == DOUT, "residual needs square");
    constexpr int KST = DIN / 32;
    constexpr int NTW = DOUT / 64;  // N-tiles per wave (block: 4 waves = DOUT/16 tiles)
    const int t = threadIdx.x;
    const int wave = t >> 6;
    const int lane = t & 63;
    const int r16 = lane & 15;
    const int kq = lane >> 4;

    const float* Af = (const float*)Av;
    const u32*   Au = (const u32*)Av;

    short8 bh[NTW][KST], bl[NTW][KST];
#pragma unroll
    for (int nt = 0; nt < NTW; nt++) {
        int ntile = wave * NTW + nt;
#pragma unroll
        for (int ks = 0; ks < KST; ks++) {
            size_t o = ((size_t)(ntile * KST + ks) * 64 + lane) * 8;
            bh[nt][ks] = *(const short8*)(fh + o);
            bl[nt][ks] = *(const short8*)(fl + o);
        }
    }

    const int m0b = blockIdx.x * (MT * 16);
#pragma unroll 1
    for (int mt = 0; mt < MT; mt++) {
        const int m0 = m0b + mt * 16;
        if (m0 >= NN) break;
        const int ra = min(m0 + r16, NN - 1);  // clamp; stores guarded

        floatx4 acc[NTW];
#pragma unroll
        for (int nt = 0; nt < NTW; nt++) acc[nt] = (floatx4){0.f, 0.f, 0.f, 0.f};

        if constexpr (AMODE == 1) {
            const float* Ap = Af + (size_t)ra * DIN + kq * 8;
#pragma unroll
            for (int ks = 0; ks < KST; ks++) {
                float4 f0 = *(const float4*)(Ap + ks * 32);
                float4 f1 = *(const float4*)(Ap + ks * 32 + 4);
                float fe[8] = {f0.x, f0.y, f0.z, f0.w, f1.x, f1.y, f1.z, f1.w};
                short8 ah;
#pragma unroll
                for (int j = 0; j < 8; j++) ah[j] = (short)f2bf(fe[j]);
#pragma unroll
                for (int nt = 0; nt < NTW; nt++) {
                    acc[nt] = __builtin_amdgcn_mfma_f32_16x16x32_bf16(ah, bh[nt][ks], acc[nt], 0, 0, 0);
                    acc[nt] = __builtin_amdgcn_mfma_f32_16x16x32_bf16(ah, bl[nt][ks], acc[nt], 0, 0, 0);
                }
            }
        } else {
            const u32* Ap = Au + (size_t)ra * DIN + kq * 8;
#pragma unroll
            for (int ks = 0; ks < KST; ks++) {
                u32x4 p0 = *(const u32x4*)(Ap + ks * 32);
                u32x4 p1 = *(const u32x4*)(Ap + ks * 32 + 4);
                short8 ah, al;
#pragma unroll
                for (int j = 0; j < 4; j++) {
                    ah[j] = (short)(p0[j] & 0xFFFFu);
                    al[j] = (short)(p0[j] >> 16);
                    ah[j + 4] = (short)(p1[j] & 0xFFFFu);
                    al[j + 4] = (short)(p1[j] >> 16);
                }
#pragma unroll
                for (int nt = 0; nt < NTW; nt++) {
                    acc[nt] = __builtin_amdgcn_mfma_f32_16x16x32_bf16(ah, bh[nt][ks], acc[nt], 0, 0, 0);
                    acc[nt] = __builtin_amdgcn_mfma_f32_16x16x32_bf16(ah, bl[nt][ks], acc[nt], 0, 0, 0);
                    acc[nt] = __builtin_amdgcn_mfma_f32_16x16x32_bf16(al, bh[nt][ks], acc[nt], 0, 0, 0);
                }
            }
        }

        // C/D layout: row = kq*4 + r, col = r16 (verified)
#pragma unroll
        for (int nt = 0; nt < NTW; nt++) {
            int col = (wave * NTW + nt) * 16 + r16;
#pragma unroll
            for (int r = 0; r < 4; r++) {
                int row = m0 + kq * 4 + r;
                if (row < NN) {
                    float v = acc[nt][r];
                    if constexpr (RESID)
                        v = fmaxf(v + unpacksplit(Au[(size_t)row * DIN + col]), 0.f);
                    if constexpr (BIAS) v = fmaxf(v + bias[col], 0.f);
                    if constexpr (SCALE) v *= dinv[row];
                    if constexpr (OMODE == 0)
                        ((float*)C)[(size_t)row * DOUT + col] = v;
                    else if constexpr (OMODE == 1)
                        ((u16*)C)[(size_t)row * DOUT + col] = f2bf(v);
                    else
                        ((u32*)C)[(size_t)row * DOUT + col] = packsplit(v);
                }
            }
        }
    }
}

// ---------------- GCN aggregation: bf16 gather payload, fp32 accumulate -------
// Output written as packed split-bf16 u32 (lossless, 4B/ch) for the consumer GEMM.
template <int D, bool BIAS_RELU>
__global__ __launch_bounds__(256) void k_agg(const u16* __restrict__ hs,
                                             const float* __restrict__ dinv,
                                             const int* __restrict__ row_ptr,
                                             const int* __restrict__ csr_src,
                                             const float* __restrict__ bias,
                                             u32* __restrict__ out) {
    constexpr int V = D / 64;
    int node = blockIdx.x * 4 + (threadIdx.x >> 6);
    int lane = threadIdx.x & 63;
    if (node >= NN) return;
    const int off = lane * V;

    float a0 = 0.f, a1 = 0.f;
    if constexpr (V == 2) {
        uint32_t u = ((const uint32_t*)(hs + (size_t)node * D))[lane];
        acc2(u, a0, a1);
    } else {
        a0 = bf2f(hs[(size_t)node * D + lane]);
    }

    int e = row_ptr[node];
    const int end = row_ptr[node + 1];

    for (; e + 8 <= end; e += 8) {
        int s[8];
#pragma unroll
        for (int i = 0; i < 8; i++) s[i] = csr_src[e + i];
        if constexpr (V == 2) {
            uint32_t v[8];
#pragma unroll
            for (int i = 0; i < 8; i++) v[i] = ((const uint32_t*)(hs + (size_t)s[i] * D))[lane];
#pragma unroll
            for (int i = 0; i < 8; i++) acc2(v[i], a0, a1);
        } else {
            u16 v[8];
#pragma unroll
            for (int i = 0; i < 8; i++) v[i] = hs[(size_t)s[i] * D + lane];
#pragma unroll
            for (int i = 0; i < 8; i++) a0 += bf2f(v[i]);
        }
    }
    for (; e + 4 <= end; e += 4) {
        int s[4];
#pragma unroll
        for (int i = 0; i < 4; i++) s[i] = csr_src[e + i];
        if constexpr (V == 2) {
            uint32_t v[4];
#pragma unroll
            for (int i = 0; i < 4; i++) v[i] = ((const uint32_t*)(hs + (size_t)s[i] * D))[lane];
#pragma unroll
            for (int i = 0; i < 4; i++) acc2(v[i], a0, a1);
        } else {
            u16 v[4];
#pragma unroll
            for (int i = 0; i < 4; i++) v[i] = hs[(size_t)s[i] * D + lane];
#pragma unroll
            for (int i = 0; i < 4; i++) a0 += bf2f(v[i]);
        }
    }
    for (; e < end; e++) {
        int s = csr_src[e];
        if constexpr (V == 2) {
            uint32_t u = ((const uint32_t*)(hs + (size_t)s * D))[lane];
            acc2(u, a0, a1);
        } else {
            a0 += bf2f(hs[(size_t)s * D + lane]);
        }
    }

    const float di = dinv[node];
    a0 *= di;
    if constexpr (V == 2) a1 *= di;
    if constexpr (BIAS_RELU) {
        a0 = fmaxf(a0 + bias[off], 0.f);
        if constexpr (V == 2) a1 = fmaxf(a1 + bias[off + 1], 0.f);
    }
    u32* po = out + (size_t)node * D + off;
    if constexpr (V == 2) {
        uint2 w;
        w.x = packsplit(a0);
        w.y = packsplit(a1);
        *(uint2*)po = w;
    } else {
        *po = packsplit(a0);
    }
}

// ---------------- launch ----------------

extern "C" void kernel_launch(void* const* d_in, const int* in_sizes, int n_in,
                              void* d_out, int out_size, void* d_ws, size_t ws_size,
                              hipStream_t stream) {
    const float* x   = (const float*)d_in[0];
    const int*   ei  = (const int*)d_in[1];
    const float* g1w = (const float*)d_in[2];
    const float* g1b = (const float*)d_in[3];
    const float* f2w = (const float*)d_in[4];
    const float* g3w = (const float*)d_in[5];
    const float* g3b = (const float*)d_in[6];
    const float* f4w = (const float*)d_in[7];
    const float* g5w = (const float*)d_in[8];
    const float* g5b = (const float*)d_in[9];
    const float* f6w = (const float*)d_in[10];
    float* out = (float*)d_out;

    const int* src = ei;       // edge_index[0]
    const int* dst = ei + NE;  // edge_index[1]

    char* p = (char*)d_ws;
    auto alloc = [&](size_t bytes) -> void* {
        void* r = (void*)p;
        p += (bytes + 255) & ~(size_t)255;
        return r;
    };
    int*   deg     = (int*)alloc(NN * 4);
    float* dinv    = (float*)alloc(NN * 4);
    int*   row_ptr = (int*)alloc((NN + 1) * 4);
    int*   bsums   = (int*)alloc(512);
    int*   gh      = (int*)alloc((NBB + 1) * 4);
    int*   gbase   = (int*)alloc((NBB + 1) * 4);
    int*   gcur    = (int*)alloc((NBB + 1) * 4);
    int*   csr     = (int*)alloc(NE * 4);
    short* wfh     = (short*)alloc(69632 * 2);
    short* wfl     = (short*)alloc(69632 * 2);
    // bufA/bufB: 4B/elem slots regardless of payload type (u16/u32/f32)
    char* bufA = (char*)alloc((size_t)NN * 128 * 4);
    char* bufB = (char*)alloc((size_t)NN * 128 * 4);
    // edge staging (12.8 MB) aliases bufB: fully consumed by k_blocal/k_bfill
    // before agg1 writes bufB (stream-ordered).
    int2* staging  = (int2*)bufB;

    const int gE4 = (NE + 4095) / 4096;      // 391
    const int gS  = (NN + 1023) / 1024;      // 98
    const int gN1 = (NN + 1 + 255) / 256;
    const int gA  = NN / 4;                  // 25000
    const int gM  = (NN + 31) / 32;          // 3125 (MT=2: 32 rows/block, exact)

    // graph preprocessing
    k_zero<<<1, 512, 0, stream>>>(gh);
    k_bhist<<<gE4, 1024, 0, stream>>>(dst, gh);
    k_bscan<<<1, 512, 0, stream>>>(gh, gbase, gcur);
    k_bscatter<<<gE4, 1024, 0, stream>>>(src, dst, gcur, staging);
    k_blocal<<<NBB, 1024, 0, stream>>>(staging, gbase, deg, dinv);
    k_scan1<<<gS, 256, 0, stream>>>(deg, row_ptr, bsums);
    k_scan2<<<1, 128, 0, stream>>>(bsums, gS);
    k_scan3<<<gN1, 256, 0, stream>>>(row_ptr, bsums);
    k_bfill<<<NBB, 1024, 0, stream>>>(staging, gbase, row_ptr, csr);

    // weight fragment prep
    {
        WPrepArgs a;
        int  eoff[6] = {0, 16384, 32768, 40960, 45056, 53248};
        int  base[6] = {0, 2048, 4096, 5120, 5632, 6656};
        int  tot[6]  = {2048, 2048, 1024, 512, 1024, 2048};
        const float* Ws[6] = {g1w, f2w, g3w, f4w, g5w, f6w};
        int din[6]  = {128, 128, 128, 64, 64, 128};
        int dout[6] = {128, 128, 64, 64, 128, 128};
        int trb[6]  = {0, 1, 0, 1, 0, 1};
        for (int i = 0; i < 6; i++) {
            a.d[i] = WDesc{Ws[i], wfh + eoff[i], wfl + eoff[i],
                           din[i], dout[i], trb[i], base[i], tot[i]};
        }
        k_wprep<<<(8704 + 255) / 256, 256, 0, stream>>>(a);
    }

    // G1: h1 = bf16(dinv * (x@W1))           [AMODE=1 fp32->bf16, OMODE=1 payload]
    k_mgemm<128, 128, 2, 1, 1, false, false, true><<<gM, 256, 0, stream>>>(
        x, wfh + 0, wfl + 0, nullptr, dinv, bufA);
    // agg1: z1 = relu(dinv*agg(h1)+b1)       [packed split out]
    k_agg<128, true><<<gA, 256, 0, stream>>>((const u16*)bufA, dinv, row_ptr, csr, g1b, (u32*)bufB);
    // fc2: z1' = relu(z1 + z1@W2^T)          [packed in+resid, packed out]
    k_mgemm<128, 128, 2, 2, 2, true, false, false><<<gM, 256, 0, stream>>>(
        bufB, wfh + 16384, wfl + 16384, nullptr, nullptr, bufA);

    // G3: h2 = bf16(dinv * (z1'@W3))         [packed in, payload out]
    k_mgemm<128, 64, 2, 2, 1, false, false, true><<<gM, 256, 0, stream>>>(
        bufA, wfh + 32768, wfl + 32768, nullptr, dinv, bufB);
    // agg2: z2 = relu(dinv*agg(h2)+b3)       [packed out]
    k_agg<64, true><<<gA, 256, 0, stream>>>((const u16*)bufB, dinv, row_ptr, csr, g3b, (u32*)bufA);
    // fc4: p3 = bf16(dinv * relu(z2 + z2@W4^T)) [packed in+resid, payload out]
    k_mgemm<64, 64, 2, 2, 1, true, false, true><<<gM, 256, 0, stream>>>(
        bufA, wfh + 40960, wfl + 40960, nullptr, dinv, bufB);

    // agg3: a3 = agg(p3)                     [packed out]
    k_agg<64, false><<<gA, 256, 0, stream>>>((const u16*)bufB, dinv, row_ptr, csr, nullptr, (u32*)bufA);
    // G5: z3 = relu(a3@W5 + b5)              [packed in, packed out]
    k_mgemm<64, 128, 2, 2, 2, false, true, false><<<gM, 256, 0, stream>>>(
        bufA, wfh + 45056, wfl + 45056, g5b, nullptr, bufB);
    // fc6: out = relu(z3 + z3@W6^T)          [packed in+resid, fp32 out]
    k_mgemm<128, 128, 2, 2, 0, true, false, false><<<gM, 256, 0, stream>>>(
        bufB, wfh + 53248, wfl + 53248, nullptr, nullptr, out);
}

// Round 4
// 504.000 us; speedup vs baseline: 1.4075x; 1.1015x over previous
//
#include <hip/hip_runtime.h>
#include <cstdint>
#include <cstddef>

#define NN 100000
#define NE 1600000
#define NBB 391   // dst buckets of 256 nodes: ceil(100000/256)

typedef short short8 __attribute__((ext_vector_type(8)));
typedef float floatx4 __attribute__((ext_vector_type(4)));
typedef uint32_t u32x4 __attribute__((ext_vector_type(4)));
typedef unsigned short u16;
typedef uint32_t u32;

// ---------------- graph preprocessing (bucketed, atomic-light) ----------------

static __global__ void k_zero(int* __restrict__ gh) {
    int i = threadIdx.x;
    if (i < NBB + 1) gh[i] = 0;
}

// histogram of dst>>8 ; 1024 thr x 4 edges/block -> 391 global atomics/block
static __global__ __launch_bounds__(1024) void k_bhist(const int* __restrict__ dst,
                                                       int* __restrict__ gh) {
    __shared__ int h[NBB + 1];
    int t = threadIdx.x;
    for (int i = t; i < NBB; i += 1024) h[i] = 0;
    __syncthreads();
    int e0 = blockIdx.x * 4096;
#pragma unroll
    for (int j = 0; j < 4; j++) {
        int e = e0 + j * 1024 + t;
        if (e < NE) atomicAdd(&h[dst[e] >> 8], 1);
    }
    __syncthreads();
    for (int i = t; i < NBB; i += 1024)
        if (h[i]) atomicAdd(&gh[i], h[i]);
}

// parallel single-block scan over NBB=391 bucket counts
static __global__ void k_bscan(const int* __restrict__ gh, int* __restrict__ gbase,
                               int* __restrict__ gcur) {
    __shared__ int sd[512];
    int t = threadIdx.x;
    int v = (t < NBB) ? gh[t] : 0;
    sd[t] = v;
    __syncthreads();
    for (int off = 1; off < 512; off <<= 1) {
        int x = (t >= off) ? sd[t - off] : 0;
        __syncthreads();
        sd[t] += x;
        __syncthreads();
    }
    int excl = (t > 0) ? sd[t - 1] : 0;
    if (t < NBB) {
        gbase[t] = excl;
        gcur[t] = excl;
    }
    if (t == NBB) gbase[NBB] = excl;  // == NE
}

// scatter edges into bucket-ordered staging (int2 = src,dst)
static __global__ __launch_bounds__(1024) void k_bscatter(const int* __restrict__ src,
                                                          const int* __restrict__ dst,
                                                          int* __restrict__ gcur,
                                                          int2* __restrict__ staging) {
    __shared__ int h[NBB + 1];
    __shared__ int base[NBB + 1];
    int t = threadIdx.x;
    for (int i = t; i < NBB; i += 1024) h[i] = 0;
    __syncthreads();
    int e0 = blockIdx.x * 4096;
    int b[4], l[4], sv[4], dv[4];
#pragma unroll
    for (int j = 0; j < 4; j++) {
        int e = e0 + j * 1024 + t;
        b[j] = -1;
        if (e < NE) {
            sv[j] = src[e];
            dv[j] = dst[e];
            b[j] = dv[j] >> 8;
            l[j] = atomicAdd(&h[b[j]], 1);
        }
    }
    __syncthreads();
    for (int i = t; i < NBB; i += 1024)
        if (h[i]) base[i] = atomicAdd(&gcur[i], h[i]);
    __syncthreads();
#pragma unroll
    for (int j = 0; j < 4; j++)
        if (b[j] >= 0) staging[base[b[j]] + l[j]] = make_int2(sv[j], dv[j]);
}

// per-bucket degree count via LDS -> deg/dinv written coalesced, no global atomics
static __global__ __launch_bounds__(1024) void k_blocal(const int2* __restrict__ staging,
                                                        const int* __restrict__ gbase,
                                                        int* __restrict__ deg,
                                                        float* __restrict__ dinv) {
    __shared__ int cnt[256];
    int b = blockIdx.x;
    int t = threadIdx.x;
    if (t < 256) cnt[t] = 0;
    __syncthreads();
    int end = gbase[b + 1];
    for (int i = gbase[b] + t; i < end; i += 1024)
        atomicAdd(&cnt[staging[i].y & 255], 1);
    __syncthreads();
    if (t < 256) {
        int node = (b << 8) + t;
        if (node < NN) {
            int d = cnt[t] + 1;  // +1 self loop
            deg[node] = d;
            dinv[node] = rsqrtf((float)d);
        }
    }
}

// exclusive scan of (deg[i]-1) -> row_ptr, chunk=1024/block
static __global__ void k_scan1(const int* __restrict__ deg, int* __restrict__ row_ptr,
                               int* __restrict__ bsums) {
    __shared__ int sd[256];
    int t = threadIdx.x;
    int base = blockIdx.x * 1024;
    int v[4];
    int s = 0;
#pragma unroll
    for (int j = 0; j < 4; j++) {
        int i = base + t * 4 + j;
        int c = (i < NN) ? (deg[i] - 1) : 0;
        v[j] = s;
        s += c;
    }
    sd[t] = s;
    __syncthreads();
    for (int off = 1; off < 256; off <<= 1) {
        int x = (t >= off) ? sd[t - off] : 0;
        __syncthreads();
        sd[t] += x;
        __syncthreads();
    }
    int excl = (t > 0) ? sd[t - 1] : 0;
#pragma unroll
    for (int j = 0; j < 4; j++) {
        int i = base + t * 4 + j;
        if (i < NN) row_ptr[i] = excl + v[j];
    }
    if (t == 255) bsums[blockIdx.x] = sd[255];
}

// parallel single-block scan over nb<=128 block sums
static __global__ void k_scan2(int* __restrict__ bsums, int nb) {
    __shared__ int sd[128];
    int t = threadIdx.x;
    int v = (t < nb) ? bsums[t] : 0;
    sd[t] = v;
    __syncthreads();
    for (int off = 1; off < 128; off <<= 1) {
        int x = (t >= off) ? sd[t - off] : 0;
        __syncthreads();
        sd[t] += x;
        __syncthreads();
    }
    if (t < nb) bsums[t] = sd[t] - v;  // exclusive
}

static __global__ void k_scan3(int* __restrict__ row_ptr, const int* __restrict__ bsums) {
    int i = blockIdx.x * 256 + threadIdx.x;
    if (i < NN) {
        row_ptr[i] += bsums[i >> 10];
    } else if (i == NN) {
        row_ptr[NN] = NE;
    }
}

// per-bucket CSR fill: ranks via LDS atomics
static __global__ __launch_bounds__(1024) void k_bfill(const int2* __restrict__ staging,
                                                       const int* __restrict__ gbase,
                                                       const int* __restrict__ row_ptr,
                                                       int* __restrict__ csr_src) {
    __shared__ int cnt[256];
    int b = blockIdx.x;
    int t = threadIdx.x;
    if (t < 256) cnt[t] = 0;
    __syncthreads();
    int end = gbase[b + 1];
    for (int i = gbase[b] + t; i < end; i += 1024) {
        int2 ed = staging[i];
        int r = atomicAdd(&cnt[ed.y & 255], 1);
        csr_src[row_ptr[ed.y] + r] = ed.x;
    }
}

// ---------------- bf16 helpers ----------------
__device__ __forceinline__ void split_bf16(float f, short& hi, short& lo) {
    union { float f; uint32_t u; } x;
    x.f = f;
    uint32_t uh = x.u + 0x7FFFu + ((x.u >> 16) & 1u);
    hi = (short)(uh >> 16);
    union { uint32_t u; float f; } hf;
    hf.u = (uh >> 16) << 16;
    float r = f - hf.f;
    union { float f; uint32_t u; } y;
    y.f = r;
    uint32_t ul = y.u + 0x7FFFu + ((y.u >> 16) & 1u);
    lo = (short)(ul >> 16);
}

__device__ __forceinline__ u16 f2bf(float f) {  // RNE
    union { float f; uint32_t u; } x;
    x.f = f;
    uint32_t r = x.u + 0x7FFFu + ((x.u >> 16) & 1u);
    return (u16)(r >> 16);
}

__device__ __forceinline__ float bf2f(u16 h) {
    union { uint32_t u; float f; } x;
    x.u = ((uint32_t)h) << 16;
    return x.f;
}

// packed split-bf16: low 16 = hi part, high 16 = lo part. hi+lo ~ fp32 (2^-16)
__device__ __forceinline__ u32 packsplit(float f) {
    short h, l;
    split_bf16(f, h, l);
    return (u32)(u16)h | ((u32)(u16)l << 16);
}

__device__ __forceinline__ float unpacksplit(u32 u) {
    return bf2f((u16)(u & 0xFFFFu)) + bf2f((u16)(u >> 16));
}

// accumulate a packed pair of bf16 (low half -> a0, high half -> a1)
__device__ __forceinline__ void acc2(uint32_t u, float& a0, float& a1) {
    union { uint32_t u; float f; } lo, hi;
    lo.u = u << 16;
    hi.u = u & 0xFFFF0000u;
    a0 += lo.f;
    a1 += hi.f;
}

// ---------------- weight pre-split into MFMA B-fragment layout ----------------
struct WDesc {
    const float* W;
    short* fh;
    short* fl;
    int din, dout, transb, base, total;  // base/total in short8 groups
};
struct WPrepArgs { WDesc d[6]; };

static __global__ void k_wprep(WPrepArgs args) {
    int tid = blockIdx.x * 256 + threadIdx.x;
#pragma unroll
    for (int i = 0; i < 6; i++) {
        const WDesc& D = args.d[i];
        if (tid >= D.base && tid < D.base + D.total) {
            int local = tid - D.base;
            int lane = local & 63;
            int rest = local >> 6;
            int kst = D.din >> 5;
            int ks = rest % kst;
            int ntile = rest / kst;
            int n = ntile * 16 + (lane & 15);
            int k0 = ks * 32 + (lane >> 4) * 8;
#pragma unroll
            for (int j = 0; j < 8; j++) {
                int k = k0 + j;
                float v = D.transb ? D.W[(size_t)n * D.din + k]
                                   : D.W[(size_t)k * D.dout + n];
                short h, l;
                split_bf16(v, h, l);
                D.fh[(size_t)local * 8 + j] = h;
                D.fl[(size_t)local * 8 + j] = l;
            }
        }
    }
}

// ---------------- MFMA GEMM: LDS-free, B in registers ------------------------
// AMODE: 1 = fp32 input, single-bf16 RNE (2 MFMAs) - only for G1 (x), whose
//            output is payload-rounded to bf16 anyway.
//        2 = packed split input (3 MFMAs, lossless vs fp32 to 2^-16)
// OMODE: 0 = fp32 out, 1 = single bf16 out (agg gather payload), 2 = packed out
template <int DIN, int DOUT, int MT, int AMODE, int OMODE, bool RESID, bool BIAS, bool SCALE>
__global__ __launch_bounds__(256) void k_mgemm(const void* __restrict__ Av,
                                               const short* __restrict__ fh,
                                               const short* __restrict__ fl,
                                               const float* __restrict__ bias,
                                               const float* __restrict__ dinv,
                                               void* __restrict__ C) {
    static_assert(!RESID || DIN == DOUT, "residual needs square");
    constexpr int KST = DIN / 32;
    constexpr int NTW = DOUT / 64;  // N-tiles per wave (block: 4 waves = DOUT/16 tiles)
    const int t = threadIdx.x;
    const int wave = t >> 6;
    const int lane = t & 63;
    const int r16 = lane & 15;
    const int kq = lane >> 4;

    const float* Af = (const float*)Av;
    const u32*   Au = (const u32*)Av;

    short8 bh[NTW][KST], bl[NTW][KST];
#pragma unroll
    for (int nt = 0; nt < NTW; nt++) {
        int ntile = wave * NTW + nt;
#pragma unroll
        for (int ks = 0; ks < KST; ks++) {
            size_t o = ((size_t)(ntile * KST + ks) * 64 + lane) * 8;
            bh[nt][ks] = *(const short8*)(fh + o);
            bl[nt][ks] = *(const short8*)(fl + o);
        }
    }

    const int m0b = blockIdx.x * (MT * 16);
#pragma unroll 1
    for (int mt = 0; mt < MT; mt++) {
        const int m0 = m0b + mt * 16;
        if (m0 >= NN) break;
        const int ra = min(m0 + r16, NN - 1);  // clamp; stores guarded

        floatx4 acc[NTW];
#pragma unroll
        for (int nt = 0; nt < NTW; nt++) acc[nt] = (floatx4){0.f, 0.f, 0.f, 0.f};

        if constexpr (AMODE == 1) {
            const float* Ap = Af + (size_t)ra * DIN + kq * 8;
#pragma unroll
            for (int ks = 0; ks < KST; ks++) {
                float4 f0 = *(const float4*)(Ap + ks * 32);
                float4 f1 = *(const float4*)(Ap + ks * 32 + 4);
                float fe[8] = {f0.x, f0.y, f0.z, f0.w, f1.x, f1.y, f1.z, f1.w};
                short8 ah;
#pragma unroll
                for (int j = 0; j < 8; j++) ah[j] = (short)f2bf(fe[j]);
#pragma unroll
                for (int nt = 0; nt < NTW; nt++) {
                    acc[nt] = __builtin_amdgcn_mfma_f32_16x16x32_bf16(ah, bh[nt][ks], acc[nt], 0, 0, 0);
                    acc[nt] = __builtin_amdgcn_mfma_f32_16x16x32_bf16(ah, bl[nt][ks], acc[nt], 0, 0, 0);
                }
            }
        } else {
            const u32* Ap = Au + (size_t)ra * DIN + kq * 8;
#pragma unroll
            for (int ks = 0; ks < KST; ks++) {
                u32x4 p0 = *(const u32x4*)(Ap + ks * 32);
                u32x4 p1 = *(const u32x4*)(Ap + ks * 32 + 4);
                short8 ah, al;
#pragma unroll
                for (int j = 0; j < 4; j++) {
                    ah[j] = (short)(p0[j] & 0xFFFFu);
                    al[j] = (short)(p0[j] >> 16);
                    ah[j + 4] = (short)(p1[j] & 0xFFFFu);
                    al[j + 4] = (short)(p1[j] >> 16);
                }
#pragma unroll
                for (int nt = 0; nt < NTW; nt++) {
                    acc[nt] = __builtin_amdgcn_mfma_f32_16x16x32_bf16(ah, bh[nt][ks], acc[nt], 0, 0, 0);
                    acc[nt] = __builtin_amdgcn_mfma_f32_16x16x32_bf16(ah, bl[nt][ks], acc[nt], 0, 0, 0);
                    acc[nt] = __builtin_amdgcn_mfma_f32_16x16x32_bf16(al, bh[nt][ks], acc[nt], 0, 0, 0);
                }
            }
        }

        // C/D layout: row = kq*4 + r, col = r16 (verified)
#pragma unroll
        for (int nt = 0; nt < NTW; nt++) {
            int col = (wave * NTW + nt) * 16 + r16;
#pragma unroll
            for (int r = 0; r < 4; r++) {
                int row = m0 + kq * 4 + r;
                if (row < NN) {
                    float v = acc[nt][r];
                    if constexpr (RESID)
                        v = fmaxf(v + unpacksplit(Au[(size_t)row * DIN + col]), 0.f);
                    if constexpr (BIAS) v = fmaxf(v + bias[col], 0.f);
                    if constexpr (SCALE) v *= dinv[row];
                    if constexpr (OMODE == 0)
                        ((float*)C)[(size_t)row * DOUT + col] = v;
                    else if constexpr (OMODE == 1)
                        ((u16*)C)[(size_t)row * DOUT + col] = f2bf(v);
                    else
                        ((u32*)C)[(size_t)row * DOUT + col] = packsplit(v);
                }
            }
        }
    }
}

// ---------------- fused GEMM pair: C = ep2( ep1(A@W1') @ W2' ) ---------------
// Round-3 lesson: fc2->G3 and G5->fc6 pass a 51.2MB intermediate through HBM
// that only the very next GEMM consumes (write+read = ~102MB each). Stage the
// 16xDMID tile through LDS instead (packed split-bf16, numerically identical
// to the global path). LDS row stride DMID+4 u32 = 528B: 16B-aligned for
// ds_read_b128, +4 banks/row -> worst 2-way conflict (free, m136).
// RESID2 adds the stage-1 result (from LDS) to stage-2's output (fc6 pattern).
template <int DIN, int DMID, int DOUT, int MT, bool RESID1, bool BIAS1,
          bool SCALE2, bool RESID2, int OMODE2>
__global__ __launch_bounds__(256) void k_mfused(const u32* __restrict__ A,
                                                const short* __restrict__ f1h,
                                                const short* __restrict__ f1l,
                                                const short* __restrict__ f2h,
                                                const short* __restrict__ f2l,
                                                const float* __restrict__ bias1,
                                                const float* __restrict__ dinv,
                                                void* __restrict__ C) {
    static_assert(!RESID1 || DIN == DMID, "resid1 needs square stage1");
    static_assert(!RESID2 || DMID == DOUT, "resid2 needs square stage2");
    constexpr int KST1 = DIN / 32;
    constexpr int NTW1 = DMID / 64;
    constexpr int KST2 = DMID / 32;
    constexpr int NTW2 = DOUT / 64;
    constexpr int LDW = DMID + 4;  // u32 stride: 16B-aligned rows, bank-skewed
    __shared__ u32 lds[16][LDW];

    const int t = threadIdx.x;
    const int wave = t >> 6;
    const int lane = t & 63;
    const int r16 = lane & 15;
    const int kq = lane >> 4;

    short8 b1h[NTW1][KST1], b1l[NTW1][KST1];
#pragma unroll
    for (int nt = 0; nt < NTW1; nt++) {
        int ntile = wave * NTW1 + nt;
#pragma unroll
        for (int ks = 0; ks < KST1; ks++) {
            size_t o = ((size_t)(ntile * KST1 + ks) * 64 + lane) * 8;
            b1h[nt][ks] = *(const short8*)(f1h + o);
            b1l[nt][ks] = *(const short8*)(f1l + o);
        }
    }
    short8 b2h[NTW2][KST2], b2l[NTW2][KST2];
#pragma unroll
    for (int nt = 0; nt < NTW2; nt++) {
        int ntile = wave * NTW2 + nt;
#pragma unroll
        for (int ks = 0; ks < KST2; ks++) {
            size_t o = ((size_t)(ntile * KST2 + ks) * 64 + lane) * 8;
            b2h[nt][ks] = *(const short8*)(f2h + o);
            b2l[nt][ks] = *(const short8*)(f2l + o);
        }
    }

    const int m0b = blockIdx.x * (MT * 16);
#pragma unroll 1
    for (int mt = 0; mt < MT; mt++) {
        const int m0 = m0b + mt * 16;
        if (m0 >= NN) break;
        const int ra = min(m0 + r16, NN - 1);

        // ---- stage 1: acc1 = A @ W1' ----
        floatx4 acc1[NTW1];
#pragma unroll
        for (int nt = 0; nt < NTW1; nt++) acc1[nt] = (floatx4){0.f, 0.f, 0.f, 0.f};
        {
            const u32* Ap = A + (size_t)ra * DIN + kq * 8;
#pragma unroll
            for (int ks = 0; ks < KST1; ks++) {
                u32x4 p0 = *(const u32x4*)(Ap + ks * 32);
                u32x4 p1 = *(const u32x4*)(Ap + ks * 32 + 4);
                short8 ah, al;
#pragma unroll
                for (int j = 0; j < 4; j++) {
                    ah[j] = (short)(p0[j] & 0xFFFFu);
                    al[j] = (short)(p0[j] >> 16);
                    ah[j + 4] = (short)(p1[j] & 0xFFFFu);
                    al[j + 4] = (short)(p1[j] >> 16);
                }
#pragma unroll
                for (int nt = 0; nt < NTW1; nt++) {
                    acc1[nt] = __builtin_amdgcn_mfma_f32_16x16x32_bf16(ah, b1h[nt][ks], acc1[nt], 0, 0, 0);
                    acc1[nt] = __builtin_amdgcn_mfma_f32_16x16x32_bf16(ah, b1l[nt][ks], acc1[nt], 0, 0, 0);
                    acc1[nt] = __builtin_amdgcn_mfma_f32_16x16x32_bf16(al, b1h[nt][ks], acc1[nt], 0, 0, 0);
                }
            }
        }
        // ---- epilogue 1 -> LDS (packed split) ----
#pragma unroll
        for (int nt = 0; nt < NTW1; nt++) {
            int col = (wave * NTW1 + nt) * 16 + r16;
#pragma unroll
            for (int r = 0; r < 4; r++) {
                int row = m0 + kq * 4 + r;
                float v = acc1[nt][r];
                if constexpr (RESID1) {
                    if (row < NN) v = fmaxf(v + unpacksplit(A[(size_t)row * DIN + col]), 0.f);
                }
                if constexpr (BIAS1) v = fmaxf(v + bias1[col], 0.f);
                lds[kq * 4 + r][col] = packsplit(v);
            }
        }
        __syncthreads();

        // ---- stage 2: acc2 = mid @ W2' (A-frags from LDS) ----
        floatx4 acc2[NTW2];
#pragma unroll
        for (int nt = 0; nt < NTW2; nt++) acc2[nt] = (floatx4){0.f, 0.f, 0.f, 0.f};
#pragma unroll
        for (int ks = 0; ks < KST2; ks++) {
            const u32* lp = &lds[r16][ks * 32 + kq * 8];
            u32x4 p0 = *(const u32x4*)lp;
            u32x4 p1 = *(const u32x4*)(lp + 4);
            short8 ah, al;
#pragma unroll
            for (int j = 0; j < 4; j++) {
                ah[j] = (short)(p0[j] & 0xFFFFu);
                al[j] = (short)(p0[j] >> 16);
                ah[j + 4] = (short)(p1[j] & 0xFFFFu);
                al[j + 4] = (short)(p1[j] >> 16);
            }
#pragma unroll
            for (int nt = 0; nt < NTW2; nt++) {
                acc2[nt] = __builtin_amdgcn_mfma_f32_16x16x32_bf16(ah, b2h[nt][ks], acc2[nt], 0, 0, 0);
                acc2[nt] = __builtin_amdgcn_mfma_f32_16x16x32_bf16(ah, b2l[nt][ks], acc2[nt], 0, 0, 0);
                acc2[nt] = __builtin_amdgcn_mfma_f32_16x16x32_bf16(al, b2h[nt][ks], acc2[nt], 0, 0, 0);
            }
        }

        // ---- epilogue 2 -> C ----
#pragma unroll
        for (int nt = 0; nt < NTW2; nt++) {
            int col = (wave * NTW2 + nt) * 16 + r16;
#pragma unroll
            for (int r = 0; r < 4; r++) {
                int row = m0 + kq * 4 + r;
                if (row < NN) {
                    float v = acc2[nt][r];
                    if constexpr (RESID2)
                        v = fmaxf(v + unpacksplit(lds[kq * 4 + r][col]), 0.f);
                    if constexpr (SCALE2) v *= dinv[row];
                    if constexpr (OMODE2 == 0)
                        ((float*)C)[(size_t)row * DOUT + col] = v;
                    else if constexpr (OMODE2 == 1)
                        ((u16*)C)[(size_t)row * DOUT + col] = f2bf(v);
                    else
                        ((u32*)C)[(size_t)row * DOUT + col] = packsplit(v);
                }
            }
        }
        __syncthreads();  // protect LDS before next mt overwrites
    }
}

// ---------------- GCN aggregation: bf16 gather payload, fp32 accumulate -------
// Output written as packed split-bf16 u32 (lossless, 4B/ch) for the consumer GEMM.
template <int D, bool BIAS_RELU>
__global__ __launch_bounds__(256) void k_agg(const u16* __restrict__ hs,
                                             const float* __restrict__ dinv,
                                             const int* __restrict__ row_ptr,
                                             const int* __restrict__ csr_src,
                                             const float* __restrict__ bias,
                                             u32* __restrict__ out) {
    constexpr int V = D / 64;
    int node = blockIdx.x * 4 + (threadIdx.x >> 6);
    int lane = threadIdx.x & 63;
    if (node >= NN) return;
    const int off = lane * V;

    float a0 = 0.f, a1 = 0.f;
    if constexpr (V == 2) {
        uint32_t u = ((const uint32_t*)(hs + (size_t)node * D))[lane];
        acc2(u, a0, a1);
    } else {
        a0 = bf2f(hs[(size_t)node * D + lane]);
    }

    int e = row_ptr[node];
    const int end = row_ptr[node + 1];

    for (; e + 8 <= end; e += 8) {
        int s[8];
#pragma unroll
        for (int i = 0; i < 8; i++) s[i] = csr_src[e + i];
        if constexpr (V == 2) {
            uint32_t v[8];
#pragma unroll
            for (int i = 0; i < 8; i++) v[i] = ((const uint32_t*)(hs + (size_t)s[i] * D))[lane];
#pragma unroll
            for (int i = 0; i < 8; i++) acc2(v[i], a0, a1);
        } else {
            u16 v[8];
#pragma unroll
            for (int i = 0; i < 8; i++) v[i] = hs[(size_t)s[i] * D + lane];
#pragma unroll
            for (int i = 0; i < 8; i++) a0 += bf2f(v[i]);
        }
    }
    for (; e + 4 <= end; e += 4) {
        int s[4];
#pragma unroll
        for (int i = 0; i < 4; i++) s[i] = csr_src[e + i];
        if constexpr (V == 2) {
            uint32_t v[4];
#pragma unroll
            for (int i = 0; i < 4; i++) v[i] = ((const uint32_t*)(hs + (size_t)s[i] * D))[lane];
#pragma unroll
            for (int i = 0; i < 4; i++) acc2(v[i], a0, a1);
        } else {
            u16 v[4];
#pragma unroll
            for (int i = 0; i < 4; i++) v[i] = hs[(size_t)s[i] * D + lane];
#pragma unroll
            for (int i = 0; i < 4; i++) a0 += bf2f(v[i]);
        }
    }
    for (; e < end; e++) {
        int s = csr_src[e];
        if constexpr (V == 2) {
            uint32_t u = ((const uint32_t*)(hs + (size_t)s * D))[lane];
            acc2(u, a0, a1);
        } else {
            a0 += bf2f(hs[(size_t)s * D + lane]);
        }
    }

    const float di = dinv[node];
    a0 *= di;
    if constexpr (V == 2) a1 *= di;
    if constexpr (BIAS_RELU) {
        a0 = fmaxf(a0 + bias[off], 0.f);
        if constexpr (V == 2) a1 = fmaxf(a1 + bias[off + 1], 0.f);
    }
    u32* po = out + (size_t)node * D + off;
    if constexpr (V == 2) {
        uint2 w;
        w.x = packsplit(a0);
        w.y = packsplit(a1);
        *(uint2*)po = w;
    } else {
        *po = packsplit(a0);
    }
}

// ---------------- launch ----------------

extern "C" void kernel_launch(void* const* d_in, const int* in_sizes, int n_in,
                              void* d_out, int out_size, void* d_ws, size_t ws_size,
                              hipStream_t stream) {
    const float* x   = (const float*)d_in[0];
    const int*   ei  = (const int*)d_in[1];
    const float* g1w = (const float*)d_in[2];
    const float* g1b = (const float*)d_in[3];
    const float* f2w = (const float*)d_in[4];
    const float* g3w = (const float*)d_in[5];
    const float* g3b = (const float*)d_in[6];
    const float* f4w = (const float*)d_in[7];
    const float* g5w = (const float*)d_in[8];
    const float* g5b = (const float*)d_in[9];
    const float* f6w = (const float*)d_in[10];
    float* out = (float*)d_out;

    const int* src = ei;       // edge_index[0]
    const int* dst = ei + NE;  // edge_index[1]

    char* p = (char*)d_ws;
    auto alloc = [&](size_t bytes) -> void* {
        void* r = (void*)p;
        p += (bytes + 255) & ~(size_t)255;
        return r;
    };
    int*   deg     = (int*)alloc(NN * 4);
    float* dinv    = (float*)alloc(NN * 4);
    int*   row_ptr = (int*)alloc((NN + 1) * 4);
    int*   bsums   = (int*)alloc(512);
    int*   gh      = (int*)alloc((NBB + 1) * 4);
    int*   gbase   = (int*)alloc((NBB + 1) * 4);
    int*   gcur    = (int*)alloc((NBB + 1) * 4);
    int*   csr     = (int*)alloc(NE * 4);
    short* wfh     = (short*)alloc(69632 * 2);
    short* wfl     = (short*)alloc(69632 * 2);
    // bufA/bufB: 4B/elem slots regardless of payload type (u16/u32/f32)
    char* bufA = (char*)alloc((size_t)NN * 128 * 4);
    char* bufB = (char*)alloc((size_t)NN * 128 * 4);
    // edge staging (12.8 MB) aliases bufB: fully consumed by k_blocal/k_bfill
    // before agg1 writes bufB (stream-ordered).
    int2* staging  = (int2*)bufB;

    const int gE4 = (NE + 4095) / 4096;      // 391
    const int gS  = (NN + 1023) / 1024;      // 98
    const int gN1 = (NN + 1 + 255) / 256;
    const int gA  = NN / 4;                  // 25000
    const int gM  = (NN + 31) / 32;          // 3125 (MT=2: 32 rows/block, exact)

    // graph preprocessing
    k_zero<<<1, 512, 0, stream>>>(gh);
    k_bhist<<<gE4, 1024, 0, stream>>>(dst, gh);
    k_bscan<<<1, 512, 0, stream>>>(gh, gbase, gcur);
    k_bscatter<<<gE4, 1024, 0, stream>>>(src, dst, gcur, staging);
    k_blocal<<<NBB, 1024, 0, stream>>>(staging, gbase, deg, dinv);
    k_scan1<<<gS, 256, 0, stream>>>(deg, row_ptr, bsums);
    k_scan2<<<1, 128, 0, stream>>>(bsums, gS);
    k_scan3<<<gN1, 256, 0, stream>>>(row_ptr, bsums);
    k_bfill<<<NBB, 1024, 0, stream>>>(staging, gbase, row_ptr, csr);

    // weight fragment prep
    {
        WPrepArgs a;
        int  eoff[6] = {0, 16384, 32768, 40960, 45056, 53248};
        int  base[6] = {0, 2048, 4096, 5120, 5632, 6656};
        int  tot[6]  = {2048, 2048, 1024, 512, 1024, 2048};
        const float* Ws[6] = {g1w, f2w, g3w, f4w, g5w, f6w};
        int din[6]  = {128, 128, 128, 64, 64, 128};
        int dout[6] = {128, 128, 64, 64, 128, 128};
        int trb[6]  = {0, 1, 0, 1, 0, 1};
        for (int i = 0; i < 6; i++) {
            a.d[i] = WDesc{Ws[i], wfh + eoff[i], wfl + eoff[i],
                           din[i], dout[i], trb[i], base[i], tot[i]};
        }
        k_wprep<<<(8704 + 255) / 256, 256, 0, stream>>>(a);
    }

    // G1: h1 = bf16(dinv * (x@W1))           [fp32 in, payload out]
    k_mgemm<128, 128, 2, 1, 1, false, false, true><<<gM, 256, 0, stream>>>(
        x, wfh + 0, wfl + 0, nullptr, dinv, bufA);
    // agg1: z1 = relu(dinv*agg(h1)+b1)       [packed split out]
    k_agg<128, true><<<gA, 256, 0, stream>>>((const u16*)bufA, dinv, row_ptr, csr, g1b, (u32*)bufB);
    // fused fc2+G3: z1' = relu(z1 + z1@W2^T); h2 = bf16(dinv*(z1'@W3))
    k_mfused<128, 128, 64, 2, true, false, true, false, 1><<<gM, 256, 0, stream>>>(
        (const u32*)bufB, wfh + 16384, wfl + 16384, wfh + 32768, wfl + 32768,
        nullptr, dinv, bufA);
    // agg2: z2 = relu(dinv*agg(h2)+b3)       [packed out]
    k_agg<64, true><<<gA, 256, 0, stream>>>((const u16*)bufA, dinv, row_ptr, csr, g3b, (u32*)bufB);
    // fc4: p3 = bf16(dinv * relu(z2 + z2@W4^T)) [packed in+resid, payload out]
    k_mgemm<64, 64, 2, 2, 1, true, false, true><<<gM, 256, 0, stream>>>(
        bufB, wfh + 40960, wfl + 40960, nullptr, dinv, bufA);
    // agg3: a3 = agg(p3)                     [packed out]
    k_agg<64, false><<<gA, 256, 0, stream>>>((const u16*)bufA, dinv, row_ptr, csr, nullptr, (u32*)bufB);
    // fused G5+fc6: z3 = relu(a3@W5+b5); out = relu(z3 + z3@W6^T)  [fp32 out]
    k_mfused<64, 128, 128, 2, false, true, false, true, 0><<<gM, 256, 0, stream>>>(
        (const u32*)bufB, wfh + 45056, wfl + 45056, wfh + 53248, wfl + 53248,
        g5b, nullptr, out);
}